// Round 2
// baseline (675.203 us; speedup 1.0000x reference)
//
#include <hip/hip_runtime.h>
#include <stdint.h>

// ---------------------------------------------------------------------------
// TransformerBlock on MI355X (gfx950). Runtime dtype detection (fp32 vs bf16
// inputs), bf16-MFMA internal compute, fp32 accumulation + fp32 residual path.
// B=2 S=2048 D=1024 H=16 K=64 MLP=4096; tokens M = 4096.
// ---------------------------------------------------------------------------

typedef unsigned short u16;
typedef __bf16 bf16x8 __attribute__((ext_vector_type(8)));
typedef float  f32x4  __attribute__((ext_vector_type(4)));

#define QSCALE 0.18033688011112042f   // (1/sqrt(64)) * log2(e): softmax via exp2

__device__ __forceinline__ float bf2f(unsigned int u) {
  union { unsigned int u; float f; } v; v.u = u << 16; return v.f;
}
__device__ __forceinline__ u16 f2bf(float f) {
  union { float f; unsigned int u; } v; v.f = f;
  unsigned int r = v.u + 0x7FFFu + ((v.u >> 16) & 1u);   // RNE
  return (u16)(r >> 16);
}
// flagged load: isf=1 -> fp32 source, else bf16 source
__device__ __forceinline__ float loadf(const void* p, size_t i, int isf) {
  return isf ? ((const float*)p)[i] : bf2f(((const u16*)p)[i]);
}

typedef const __attribute__((address_space(1))) void* gas_t;
typedef __attribute__((address_space(3))) void* las_t;
__device__ __forceinline__ void gl_lds16(const u16* g, u16* l) {
  __builtin_amdgcn_global_load_lds((gas_t)g, (las_t)l, 16, 0, 0);
}

// ---------------------------------------------------------------------------
// dtype detect: fp32 N(0,1) words have fp32-exponent in [97,157]; bf16-packed
// words (elem(2i+1)<<16|elem(2i)) have exponent-field = 2*(e&127)+m6 ~ 224..255.
// ---------------------------------------------------------------------------
__global__ __launch_bounds__(256) void detect_dtype(
    const unsigned int* __restrict__ x, int* __restrict__ flag) {
  __shared__ int cnt;
  if (threadIdx.x == 0) cnt = 0;
  __syncthreads();
  int c = 0;
  for (int i = threadIdx.x; i < 512; i += 256) {
    unsigned int e = (x[i] >> 23) & 0xFFu;
    if (e >= 97u && e <= 157u) c++;
  }
  atomicAdd(&cnt, c);
  __syncthreads();
  if (threadIdx.x == 0) *flag = (cnt > 384) ? 1 : 0;
}

// ---------------------------------------------------------------------------
// Weight packing: B^T [N][K] row-major, so MFMA B-frags are contiguous in k.
// ---------------------------------------------------------------------------
__global__ __launch_bounds__(256) void pack_qkvT(
    const int* __restrict__ flagp,
    const void* __restrict__ Wq, const void* __restrict__ Wk, const void* __restrict__ Wv,
    u16* __restrict__ WT) {
  const int isf = *flagp;
  size_t idx = (size_t)blockIdx.x * 256 + threadIdx.x;   // 3072*1024 threads
  int c = (int)(idx >> 10);          // output feature 0..3071
  int d = (int)(idx & 1023);         // d_model
  int hk = c & 1023;
  int h = hk >> 6, k = hk & 63;
  size_t widx = ((size_t)h << 16) + ((size_t)d << 6) + (size_t)k;  // W[h,d,k]
  float v;
  if (c < 1024)       v = loadf(Wq, widx, isf) * QSCALE;  // fold softmax scale into Q
  else if (c < 2048)  v = loadf(Wk, widx, isf);
  else                v = loadf(Wv, widx, isf);
  WT[idx] = f2bf(v);
}

// all biases -> fp32 ws array: [0,3072) qkv (Q scaled), [3072,4096) bO,
// [4096,8192) b_in, [8192,9216) b_out
__global__ __launch_bounds__(256) void pack_biases(
    const int* __restrict__ flagp,
    const void* bq, const void* bk, const void* bv,
    const void* bO, const void* bin, const void* bout,
    float* __restrict__ out) {
  const int isf = *flagp;
  int i = blockIdx.x * 256 + threadIdx.x;   // 0..9215
  float v;
  if (i < 1024)      v = loadf(bq,   i,        isf) * QSCALE;
  else if (i < 2048) v = loadf(bk,   i - 1024, isf);
  else if (i < 3072) v = loadf(bv,   i - 2048, isf);
  else if (i < 4096) v = loadf(bO,   i - 3072, isf);
  else if (i < 8192) v = loadf(bin,  i - 4096, isf);
  else               v = loadf(bout, i - 8192, isf);
  out[i] = v;
}

// dst[C][R] = src[R][C]^T ; R = 1<<lr  (src flagged dtype, dst bf16)
__global__ __launch_bounds__(256) void transpose_any(
    const int* __restrict__ flagp, const void* __restrict__ src,
    u16* __restrict__ dst, int lr, int C) {
  const int isf = *flagp;
  size_t idx = (size_t)blockIdx.x * 256 + threadIdx.x;
  size_t r = idx & (((size_t)1 << lr) - 1);
  size_t c = idx >> lr;
  dst[idx] = f2bf(loadf(src, r * (size_t)C + c, isf));
}

// ---------------------------------------------------------------------------
// LayerNorm over D=1024: one block (256 thr) per row, 4 elems/thread, fp32 stats
// SRC=0: external input (flag dtype). SRC=1: fp32 ws input. w,b always flagged.
// ---------------------------------------------------------------------------
template<int SRC>
__global__ __launch_bounds__(256) void ln_fwd(
    const int* __restrict__ flagp, const void* __restrict__ xin,
    const void* __restrict__ w, const void* __restrict__ b,
    u16* __restrict__ out) {
  const int isf = *flagp;
  const int row = blockIdx.x, tid = threadIdx.x;
  const int col = tid << 2;
  const size_t base = ((size_t)row << 10) + col;
  float v[4];
#pragma unroll
  for (int i = 0; i < 4; i++)
    v[i] = (SRC == 1) ? ((const float*)xin)[base + i] : loadf(xin, base + i, isf);
  float s  = v[0] + v[1] + v[2] + v[3];
  float ss = v[0]*v[0] + v[1]*v[1] + v[2]*v[2] + v[3]*v[3];
#pragma unroll
  for (int mk = 32; mk >= 1; mk >>= 1) {
    s  += __shfl_xor(s,  mk, 64);
    ss += __shfl_xor(ss, mk, 64);
  }
  __shared__ float red[8];
  if ((tid & 63) == 0) { red[tid >> 6] = s; red[4 + (tid >> 6)] = ss; }
  __syncthreads();
  float S  = red[0] + red[1] + red[2] + red[3];
  float SS = red[4] + red[5] + red[6] + red[7];
  float mean = S * (1.f / 1024.f);
  float var  = SS * (1.f / 1024.f) - mean * mean;   // population var == jnp.var
  float rstd = rsqrtf(var + 1e-5f);
  u16 e[4];
#pragma unroll
  for (int i = 0; i < 4; i++) {
    float wv = loadf(w, col + i, isf);
    float bv = loadf(b, col + i, isf);
    e[i] = f2bf((v[i] - mean) * rstd * wv + bv);
  }
  uint2 o;
  o.x = (unsigned)e[0] | ((unsigned)e[1] << 16);
  o.y = (unsigned)e[2] | ((unsigned)e[3] << 16);
  *(uint2*)(out + base) = o;
}

// ---------------------------------------------------------------------------
// GEMM C[M,N] = A[M,K] @ BT[N,K]^T + bias, m97 structure:
// 128x128 tile, BK=32, 4 waves (64x64 each), global_load_lds w=16.
// MODE 0: bf16 out; 1: relu+bf16; 2: +flagged resid -> fp32 out;
// MODE 3: +fp32 resid -> flagged out (d_out)
// ---------------------------------------------------------------------------
template<int MODE>
__global__ __launch_bounds__(256) void gemm_bt(
    const int* __restrict__ flagp,
    const u16* __restrict__ A, const u16* __restrict__ BT,
    const float* __restrict__ bias, const void* __restrict__ resid,
    void* __restrict__ out, int M, int N, int K) {
  __shared__ u16 as[128 * 32];
  __shared__ u16 bs[128 * 32];
  int isf = 0;
  if (MODE >= 2) isf = *flagp;
  const int tid = threadIdx.x;
  const int L = tid & 63, w = tid >> 6;
  const int wm = (w >> 1) << 6, wn = (w & 1) << 6;
  const int row0 = blockIdx.y << 7, col0 = blockIdx.x << 7;
  const int m = L & 15, quad = L >> 4;

  f32x4 zero4 = {0.f, 0.f, 0.f, 0.f};
  f32x4 acc[4][4];
#pragma unroll
  for (int i = 0; i < 4; i++)
#pragma unroll
    for (int j = 0; j < 4; j++) acc[i][j] = zero4;

  const int tm = tid >> 2;            // staging row 0..63
  const int tk = (tid & 3) << 3;      // staging k-chunk
  const u16* Ag  = A  + (size_t)(row0 + tm) * K + tk;
  const u16* Ag2 = Ag + (size_t)64 * K;
  const u16* Bg  = BT + (size_t)(col0 + tm) * K + tk;
  const u16* Bg2 = Bg + (size_t)64 * K;
  u16* asl  = &as[tid * 8];
  u16* asl2 = &as[2048 + tid * 8];
  u16* bsl  = &bs[tid * 8];
  u16* bsl2 = &bs[2048 + tid * 8];

  const int aoff = (wm + m) * 32 + quad * 8;
  const int boff = (wn + m) * 32 + quad * 8;

  for (int kk = 0; kk < K; kk += 32) {
    __syncthreads();
    gl_lds16(Ag  + kk, asl);
    gl_lds16(Ag2 + kk, asl2);
    gl_lds16(Bg  + kk, bsl);
    gl_lds16(Bg2 + kk, bsl2);
    __syncthreads();
    bf16x8 af[4], bfr[4];
#pragma unroll
    for (int i = 0; i < 4; i++) af[i]  = *(const bf16x8*)&as[aoff + i * (16 * 32)];
#pragma unroll
    for (int j = 0; j < 4; j++) bfr[j] = *(const bf16x8*)&bs[boff + j * (16 * 32)];
#pragma unroll
    for (int i = 0; i < 4; i++)
#pragma unroll
      for (int j = 0; j < 4; j++)
        acc[i][j] = __builtin_amdgcn_mfma_f32_16x16x32_bf16(af[i], bfr[j], acc[i][j], 0, 0, 0);
  }

#pragma unroll
  for (int j = 0; j < 4; j++) {
    const int col = col0 + wn + j * 16 + m;
    const float bval = bias[col];
#pragma unroll
    for (int i = 0; i < 4; i++) {
      const int rowb = row0 + wm + i * 16 + quad * 4;
#pragma unroll
      for (int r = 0; r < 4; r++) {
        float vv = acc[i][j][r] + bval;
        size_t idx = (size_t)(rowb + r) * N + col;
        if (MODE == 0) {
          ((u16*)out)[idx] = f2bf(vv);
        } else if (MODE == 1) {
          ((u16*)out)[idx] = f2bf(fmaxf(vv, 0.f));
        } else if (MODE == 2) {
          ((float*)out)[idx] = vv + loadf(resid, idx, isf);
        } else {
          float o = vv + ((const float*)resid)[idx];
          if (isf) ((float*)out)[idx] = o;
          else     ((u16*)out)[idx]   = f2bf(o);
        }
      }
    }
  }
}

// ---------------------------------------------------------------------------
// Flash attention, causal. Block = 64 q rows (4 waves x 16), head dim 64.
// qkv: [4096 tokens][3072] (Q|K|V each h*64+k), Q pre-scaled by QSCALE.
// Softmax in exp2 domain. z: [4096][1024].
// ---------------------------------------------------------------------------
__global__ __launch_bounds__(256) void attn_fwd(
    const u16* __restrict__ qkv, u16* __restrict__ z) {
  __shared__ u16 Vt[64 * 72];          // V transposed [feat][tok], pad 72
  __shared__ u16 Pls[4 * 16 * 72];     // per-wave P [16][72]
  const int tid = threadIdx.x, L = tid & 63, w = tid >> 6;
  const int m = L & 15, quad = L >> 4;
  const int q0 = blockIdx.x << 6;
  const int h = blockIdx.y;
  const int b = blockIdx.z;
  const size_t tb = (size_t)b * 2048;

  bf16x8 aq[2];   // Q A-frags: rows m, k = feature
  {
    const u16* qp = qkv + (tb + q0 + w * 16 + m) * 3072 + h * 64 + quad * 8;
    aq[0] = *(const bf16x8*)qp;
    aq[1] = *(const bf16x8*)(qp + 32);
  }

  f32x4 zero4 = {0.f, 0.f, 0.f, 0.f};
  f32x4 O[4];
#pragma unroll
  for (int fb = 0; fb < 4; fb++) O[fb] = zero4;
  float mrow[4] = {-30000.f, -30000.f, -30000.f, -30000.f};
  float lrow[4] = {0.f, 0.f, 0.f, 0.f};

  const int jmax = q0 >> 6;
  for (int j = 0; j <= jmax; j++) {
    const int k0 = j << 6;
    // stage V transposed: consecutive lanes -> consecutive tokens (conflict-free)
#pragma unroll
    for (int it = 0; it < 2; it++) {
      int c = it * 256 + tid;
      int tok = c & 63, f0 = (c >> 6) << 3;
      const u16* vp = qkv + (tb + k0 + tok) * 3072 + 2048 + h * 64 + f0;
      union { int4 v; u16 u[8]; } tmp;
      tmp.v = *(const int4*)vp;
#pragma unroll
      for (int e = 0; e < 8; e++) Vt[(f0 + e) * 72 + tok] = tmp.u[e];
    }
    // S = Q K^T (K B-frags straight from global: 16B/lane, contiguous features)
    f32x4 sacc[4];
    {
      const u16* kb = qkv + (tb + k0) * 3072 + 1024 + h * 64 + quad * 8;
#pragma unroll
      for (int cb = 0; cb < 4; cb++) {
        const u16* kp = kb + (size_t)(cb * 16 + m) * 3072;
        bf16x8 bk0 = *(const bf16x8*)kp;
        bf16x8 bk1 = *(const bf16x8*)(kp + 32);
        f32x4 t = zero4;
        t = __builtin_amdgcn_mfma_f32_16x16x32_bf16(aq[0], bk0, t, 0, 0, 0);
        t = __builtin_amdgcn_mfma_f32_16x16x32_bf16(aq[1], bk1, t, 0, 0, 0);
        sacc[cb] = t;
      }
    }
    if (j == jmax) {   // diagonal tile: causal mask (C/D: row=quad*4+r, col=m)
#pragma unroll
      for (int cb = 0; cb < 4; cb++)
#pragma unroll
        for (int r = 0; r < 4; r++) {
          int rowg = q0 + w * 16 + quad * 4 + r;
          int colg = k0 + cb * 16 + m;
          if (colg > rowg) sacc[cb][r] = -30000.f;
        }
    }
    // online softmax per row (reduce across 16 lanes of the row group)
    float pr[4][4];
#pragma unroll
    for (int r = 0; r < 4; r++) {
      float mx = fmaxf(fmaxf(sacc[0][r], sacc[1][r]), fmaxf(sacc[2][r], sacc[3][r]));
      mx = fmaxf(mx, __shfl_xor(mx, 1, 64));
      mx = fmaxf(mx, __shfl_xor(mx, 2, 64));
      mx = fmaxf(mx, __shfl_xor(mx, 4, 64));
      mx = fmaxf(mx, __shfl_xor(mx, 8, 64));
      float mnew = fmaxf(mrow[r], mx);
      float alpha = exp2f(mrow[r] - mnew);
      float sum = 0.f;
#pragma unroll
      for (int cb = 0; cb < 4; cb++) {
        float p = exp2f(sacc[cb][r] - mnew);
        pr[cb][r] = p; sum += p;
      }
      sum += __shfl_xor(sum, 1, 64);
      sum += __shfl_xor(sum, 2, 64);
      sum += __shfl_xor(sum, 4, 64);
      sum += __shfl_xor(sum, 8, 64);
      lrow[r] = lrow[r] * alpha + sum;
      mrow[r] = mnew;
#pragma unroll
      for (int fb = 0; fb < 4; fb++) O[fb][r] *= alpha;
    }
    // P: C-layout -> LDS -> A-layout
    u16* pw = &Pls[w * (16 * 72)];
#pragma unroll
    for (int cb = 0; cb < 4; cb++)
#pragma unroll
      for (int r = 0; r < 4; r++)
        pw[(quad * 4 + r) * 72 + cb * 16 + m] = f2bf(pr[cb][r]);
    __syncthreads();
    bf16x8 ap0 = *(const bf16x8*)&pw[m * 72 + quad * 8];
    bf16x8 ap1 = *(const bf16x8*)&pw[m * 72 + 32 + quad * 8];
#pragma unroll
    for (int fb = 0; fb < 4; fb++) {
      bf16x8 bv0 = *(const bf16x8*)&Vt[(fb * 16 + m) * 72 + quad * 8];
      bf16x8 bv1 = *(const bf16x8*)&Vt[(fb * 16 + m) * 72 + 32 + quad * 8];
      O[fb] = __builtin_amdgcn_mfma_f32_16x16x32_bf16(ap0, bv0, O[fb], 0, 0, 0);
      O[fb] = __builtin_amdgcn_mfma_f32_16x16x32_bf16(ap1, bv1, O[fb], 0, 0, 0);
    }
    __syncthreads();
  }
#pragma unroll
  for (int fb = 0; fb < 4; fb++)
#pragma unroll
    for (int r = 0; r < 4; r++) {
      size_t tok = tb + q0 + w * 16 + quad * 4 + r;
      z[tok * 1024 + h * 64 + fb * 16 + m] = f2bf(O[fb][r] / lrow[r]);
    }
}

// ---------------------------------------------------------------------------
extern "C" void kernel_launch(void* const* d_in, const int* in_sizes, int n_in,
                              void* d_out, int out_size, void* d_ws, size_t ws_size,
                              hipStream_t stream) {
  (void)in_sizes; (void)n_in; (void)out_size; (void)ws_size;
  const void* resid_pre = d_in[0];
  const void* ln1_w = d_in[1];
  const void* ln1_b = d_in[2];
  const void* W_Q   = d_in[3];
  const void* b_Q   = d_in[4];
  const void* W_K   = d_in[5];
  const void* b_K   = d_in[6];
  const void* W_V   = d_in[7];
  const void* b_V   = d_in[8];
  const void* W_O   = d_in[9];
  const void* b_O   = d_in[10];
  const void* ln2_w = d_in[11];
  const void* ln2_b = d_in[12];
  const void* W_in  = d_in[13];
  const void* b_in  = d_in[14];
  const void* W_out = d_in[15];
  const void* b_out = d_in[16];

  char* p = (char*)d_ws;
  auto alloc = [&](size_t bytes) {
    char* r = p; p += (bytes + 255) & ~(size_t)255; return (void*)r;
  };
  int*   flag      = (int*)  alloc(256);
  u16*   WqkvT     = (u16*)  alloc(3072ull * 1024 * 2);
  u16*   WoT       = (u16*)  alloc(1024ull * 1024 * 2);
  u16*   WinT      = (u16*)  alloc(4096ull * 1024 * 2);
  u16*   WoutT     = (u16*)  alloc(1024ull * 4096 * 2);
  float* biases    = (float*)alloc(9216 * 4);
  u16*   xn        = (u16*)  alloc(4096ull * 1024 * 2);  // reused as z after QKV GEMM
  u16*   qkv       = (u16*)  alloc(4096ull * 3072 * 2);
  float* resid_mid = (float*)alloc(4096ull * 1024 * 4);
  u16*   h2        = (u16*)  alloc(4096ull * 1024 * 2);
  u16*   act       = (u16*)  alloc(4096ull * 4096 * 2);
  u16*   z = xn;

  // dtype flag first; everything else depends on it
  detect_dtype<<<1, 256, 0, stream>>>((const unsigned int*)resid_pre, flag);

  // weight packs
  pack_qkvT<<<3072 * 1024 / 256, 256, 0, stream>>>(flag, W_Q, W_K, W_V, WqkvT);
  transpose_any<<<1024 * 1024 / 256, 256, 0, stream>>>(flag, W_O,   WoT,   10, 1024);
  transpose_any<<<1024 * 4096 / 256, 256, 0, stream>>>(flag, W_in,  WinT,  10, 4096);
  transpose_any<<<4096 * 1024 / 256, 256, 0, stream>>>(flag, W_out, WoutT, 12, 1024);
  pack_biases<<<36, 256, 0, stream>>>(flag, b_Q, b_K, b_V, b_O, b_in, b_out, biases);

  // ln1 -> xn
  ln_fwd<0><<<4096, 256, 0, stream>>>(flag, resid_pre, ln1_w, ln1_b, xn);
  // qkv = xn @ [Wq*s | Wk | Wv] + bias
  gemm_bt<0><<<dim3(3072 / 128, 4096 / 128), 256, 0, stream>>>(
      flag, xn, WqkvT, biases, nullptr, qkv, 4096, 3072, 1024);
  // causal flash attention -> z
  attn_fwd<<<dim3(2048 / 64, 16, 2), 256, 0, stream>>>(qkv, z);
  // resid_mid = resid_pre + z @ W_O + b_O   (fp32)
  gemm_bt<2><<<dim3(1024 / 128, 4096 / 128), 256, 0, stream>>>(
      flag, z, WoT, biases + 3072, resid_pre, resid_mid, 4096, 1024, 1024);
  // ln2 -> h2
  ln_fwd<1><<<4096, 256, 0, stream>>>(flag, resid_mid, ln2_w, ln2_b, h2);
  // act = relu(h2 @ W_in + b_in)
  gemm_bt<1><<<dim3(4096 / 128, 4096 / 128), 256, 0, stream>>>(
      flag, h2, WinT, biases + 4096, nullptr, act, 4096, 4096, 1024);
  // out = resid_mid + act @ W_out + b_out
  gemm_bt<3><<<dim3(1024 / 128, 4096 / 128), 256, 0, stream>>>(
      flag, act, WoutT, biases + 8192, resid_mid, d_out, 4096, 1024, 4096);
}

// Round 3
// 556.173 us; speedup vs baseline: 1.2140x; 1.2140x over previous
//
#include <hip/hip_runtime.h>
#include <stdint.h>

// ---------------------------------------------------------------------------
// TransformerBlock on MI355X (gfx950). Runtime dtype detection (fp32 vs bf16
// inputs), bf16-MFMA internal compute, fp32 accumulation + fp32 residual path.
// B=2 S=2048 D=1024 H=16 K=64 MLP=4096; tokens M = 4096.
// R3: attention rewrite — balanced causal pairing, head-major QKV + pre-
// transposed V from the QKV GEMM epilogue, 128-token k-steps, padded-LDS
// staging with register software pipeline.
// ---------------------------------------------------------------------------

typedef unsigned short u16;
typedef __bf16 bf16x8 __attribute__((ext_vector_type(8)));
typedef float  f32x4  __attribute__((ext_vector_type(4)));

#define QSCALE 0.18033688011112042f   // (1/sqrt(64)) * log2(e): softmax via exp2

__device__ __forceinline__ float bf2f(unsigned int u) {
  union { unsigned int u; float f; } v; v.u = u << 16; return v.f;
}
__device__ __forceinline__ u16 f2bf(float f) {
  union { float f; unsigned int u; } v; v.f = f;
  unsigned int r = v.u + 0x7FFFu + ((v.u >> 16) & 1u);   // RNE
  return (u16)(r >> 16);
}
__device__ __forceinline__ float loadf(const void* p, size_t i, int isf) {
  return isf ? ((const float*)p)[i] : bf2f(((const u16*)p)[i]);
}

typedef const __attribute__((address_space(1))) void* gas_t;
typedef __attribute__((address_space(3))) void* las_t;
__device__ __forceinline__ void gl_lds16(const u16* g, u16* l) {
  __builtin_amdgcn_global_load_lds((gas_t)g, (las_t)l, 16, 0, 0);
}

// ---------------------------------------------------------------------------
__global__ __launch_bounds__(256) void detect_dtype(
    const unsigned int* __restrict__ x, int* __restrict__ flag) {
  __shared__ int cnt;
  if (threadIdx.x == 0) cnt = 0;
  __syncthreads();
  int c = 0;
  for (int i = threadIdx.x; i < 512; i += 256) {
    unsigned int e = (x[i] >> 23) & 0xFFu;
    if (e >= 97u && e <= 157u) c++;
  }
  atomicAdd(&cnt, c);
  __syncthreads();
  if (threadIdx.x == 0) *flag = (cnt > 384) ? 1 : 0;
}

// ---------------------------------------------------------------------------
__global__ __launch_bounds__(256) void pack_qkvT(
    const int* __restrict__ flagp,
    const void* __restrict__ Wq, const void* __restrict__ Wk, const void* __restrict__ Wv,
    u16* __restrict__ WT) {
  const int isf = *flagp;
  size_t idx = (size_t)blockIdx.x * 256 + threadIdx.x;
  int c = (int)(idx >> 10);
  int d = (int)(idx & 1023);
  int hk = c & 1023;
  int h = hk >> 6, k = hk & 63;
  size_t widx = ((size_t)h << 16) + ((size_t)d << 6) + (size_t)k;
  float v;
  if (c < 1024)       v = loadf(Wq, widx, isf) * QSCALE;
  else if (c < 2048)  v = loadf(Wk, widx, isf);
  else                v = loadf(Wv, widx, isf);
  WT[idx] = f2bf(v);
}

__global__ __launch_bounds__(256) void pack_biases(
    const int* __restrict__ flagp,
    const void* bq, const void* bk, const void* bv,
    const void* bO, const void* bin, const void* bout,
    float* __restrict__ out) {
  const int isf = *flagp;
  int i = blockIdx.x * 256 + threadIdx.x;
  float v;
  if (i < 1024)      v = loadf(bq,   i,        isf) * QSCALE;
  else if (i < 2048) v = loadf(bk,   i - 1024, isf);
  else if (i < 3072) v = loadf(bv,   i - 2048, isf);
  else if (i < 4096) v = loadf(bO,   i - 3072, isf);
  else if (i < 8192) v = loadf(bin,  i - 4096, isf);
  else               v = loadf(bout, i - 8192, isf);
  out[i] = v;
}

__global__ __launch_bounds__(256) void transpose_any(
    const int* __restrict__ flagp, const void* __restrict__ src,
    u16* __restrict__ dst, int lr, int C) {
  const int isf = *flagp;
  size_t idx = (size_t)blockIdx.x * 256 + threadIdx.x;
  size_t r = idx & (((size_t)1 << lr) - 1);
  size_t c = idx >> lr;
  dst[idx] = f2bf(loadf(src, r * (size_t)C + c, isf));
}

// ---------------------------------------------------------------------------
template<int SRC>
__global__ __launch_bounds__(256) void ln_fwd(
    const int* __restrict__ flagp, const void* __restrict__ xin,
    const void* __restrict__ w, const void* __restrict__ b,
    u16* __restrict__ out) {
  const int isf = *flagp;
  const int row = blockIdx.x, tid = threadIdx.x;
  const int col = tid << 2;
  const size_t base = ((size_t)row << 10) + col;
  float v[4];
#pragma unroll
  for (int i = 0; i < 4; i++)
    v[i] = (SRC == 1) ? ((const float*)xin)[base + i] : loadf(xin, base + i, isf);
  float s  = v[0] + v[1] + v[2] + v[3];
  float ss = v[0]*v[0] + v[1]*v[1] + v[2]*v[2] + v[3]*v[3];
#pragma unroll
  for (int mk = 32; mk >= 1; mk >>= 1) {
    s  += __shfl_xor(s,  mk, 64);
    ss += __shfl_xor(ss, mk, 64);
  }
  __shared__ float red[8];
  if ((tid & 63) == 0) { red[tid >> 6] = s; red[4 + (tid >> 6)] = ss; }
  __syncthreads();
  float S  = red[0] + red[1] + red[2] + red[3];
  float SS = red[4] + red[5] + red[6] + red[7];
  float mean = S * (1.f / 1024.f);
  float var  = SS * (1.f / 1024.f) - mean * mean;
  float rstd = rsqrtf(var + 1e-5f);
  u16 e[4];
#pragma unroll
  for (int i = 0; i < 4; i++) {
    float wv = loadf(w, col + i, isf);
    float bv = loadf(b, col + i, isf);
    e[i] = f2bf((v[i] - mean) * rstd * wv + bv);
  }
  uint2 o;
  o.x = (unsigned)e[0] | ((unsigned)e[1] << 16);
  o.y = (unsigned)e[2] | ((unsigned)e[3] << 16);
  *(uint2*)(out + base) = o;
}

// ---------------------------------------------------------------------------
// GEMM C[M,N] = A[M,K] @ BT[N,K]^T + bias, m97 structure.
// MODE 0: bf16 out; 1: relu+bf16; 2: +flagged resid -> fp32 out;
// MODE 3: +fp32 resid -> flagged out (d_out)
// MODE 4: QKV epilogue -> q_hm[h][t][64] (out), k_hm (out2), vT[h][f][4096] (out3)
// ---------------------------------------------------------------------------
template<int MODE>
__global__ __launch_bounds__(256) void gemm_bt(
    const int* __restrict__ flagp,
    const u16* __restrict__ A, const u16* __restrict__ BT,
    const float* __restrict__ bias, const void* __restrict__ resid,
    void* __restrict__ out, void* __restrict__ out2, void* __restrict__ out3,
    int M, int N, int K) {
  __shared__ u16 as[128 * 32];
  __shared__ u16 bs[128 * 32];
  int isf = 0;
  if (MODE == 2 || MODE == 3) isf = *flagp;
  const int tid = threadIdx.x;
  const int L = tid & 63, w = tid >> 6;
  const int wm = (w >> 1) << 6, wn = (w & 1) << 6;
  const int row0 = blockIdx.y << 7, col0 = blockIdx.x << 7;
  const int m = L & 15, quad = L >> 4;

  f32x4 zero4 = {0.f, 0.f, 0.f, 0.f};
  f32x4 acc[4][4];
#pragma unroll
  for (int i = 0; i < 4; i++)
#pragma unroll
    for (int j = 0; j < 4; j++) acc[i][j] = zero4;

  const int tm = tid >> 2;
  const int tk = (tid & 3) << 3;
  const u16* Ag  = A  + (size_t)(row0 + tm) * K + tk;
  const u16* Ag2 = Ag + (size_t)64 * K;
  const u16* Bg  = BT + (size_t)(col0 + tm) * K + tk;
  const u16* Bg2 = Bg + (size_t)64 * K;
  u16* asl  = &as[tid * 8];
  u16* asl2 = &as[2048 + tid * 8];
  u16* bsl  = &bs[tid * 8];
  u16* bsl2 = &bs[2048 + tid * 8];

  const int aoff = (wm + m) * 32 + quad * 8;
  const int boff = (wn + m) * 32 + quad * 8;

  for (int kk = 0; kk < K; kk += 32) {
    __syncthreads();
    gl_lds16(Ag  + kk, asl);
    gl_lds16(Ag2 + kk, asl2);
    gl_lds16(Bg  + kk, bsl);
    gl_lds16(Bg2 + kk, bsl2);
    __syncthreads();
    bf16x8 af[4], bfr[4];
#pragma unroll
    for (int i = 0; i < 4; i++) af[i]  = *(const bf16x8*)&as[aoff + i * (16 * 32)];
#pragma unroll
    for (int j = 0; j < 4; j++) bfr[j] = *(const bf16x8*)&bs[boff + j * (16 * 32)];
#pragma unroll
    for (int i = 0; i < 4; i++)
#pragma unroll
      for (int j = 0; j < 4; j++)
        acc[i][j] = __builtin_amdgcn_mfma_f32_16x16x32_bf16(af[i], bfr[j], acc[i][j], 0, 0, 0);
  }

#pragma unroll
  for (int j = 0; j < 4; j++) {
    const int col = col0 + wn + j * 16 + m;
    const float bval = bias[col];
    if (MODE == 4) {
      const int sel = col >> 10;
      const int hh  = (col >> 6) & 15;
      const int f   = col & 63;
#pragma unroll
      for (int i = 0; i < 4; i++) {
        const int rowb = row0 + wm + i * 16 + quad * 4;
        if (sel < 2) {
          u16* dst = (u16*)(sel ? out2 : out);
#pragma unroll
          for (int r = 0; r < 4; r++)
            dst[(((size_t)hh << 12) + rowb + r << 6) + f] = f2bf(acc[i][j][r] + bval);
        } else {
          u16 e[4];
#pragma unroll
          for (int r = 0; r < 4; r++) e[r] = f2bf(acc[i][j][r] + bval);
          uint2 o;
          o.x = (unsigned)e[0] | ((unsigned)e[1] << 16);
          o.y = (unsigned)e[2] | ((unsigned)e[3] << 16);
          *(uint2*)&((u16*)out3)[(((size_t)hh * 64 + f) << 12) + rowb] = o;
        }
      }
    } else {
#pragma unroll
      for (int i = 0; i < 4; i++) {
        const int rowb = row0 + wm + i * 16 + quad * 4;
#pragma unroll
        for (int r = 0; r < 4; r++) {
          float vv = acc[i][j][r] + bval;
          size_t idx = (size_t)(rowb + r) * N + col;
          if (MODE == 0) {
            ((u16*)out)[idx] = f2bf(vv);
          } else if (MODE == 1) {
            ((u16*)out)[idx] = f2bf(fmaxf(vv, 0.f));
          } else if (MODE == 2) {
            ((float*)out)[idx] = vv + loadf(resid, idx, isf);
          } else if (MODE == 3) {
            float o = vv + ((const float*)resid)[idx];
            if (isf) ((float*)out)[idx] = o;
            else     ((u16*)out)[idx]   = f2bf(o);
          }
        }
      }
    }
  }
}

// ---------------------------------------------------------------------------
// Flash attention, causal, balanced. Block = 4 waves; processes q-tiles
// (pairI, 31-pairI), 64 rows each (16/wave). k-step 128. Head-major inputs:
// qh/kh [h][4096][64] (Q pre-scaled by QSCALE), vT [h][64][4096].
// Constant work: 17 k-steps per block. z: [t][1024] token-major.
// ---------------------------------------------------------------------------
__global__ __launch_bounds__(256) void attn_fwd(
    const u16* __restrict__ qh, const u16* __restrict__ kh,
    const u16* __restrict__ vT, u16* __restrict__ z) {
  __shared__ u16 kS[128 * 72];       // K tile [tok][64+8 pad]
  __shared__ u16 vS[64 * 136];       // V^T tile [f][128+8 pad]
  __shared__ u16 pS[4 * 16 * 136];   // per-wave P [16][128+8 pad]
  const int tid = threadIdx.x, L = tid & 63, w = tid >> 6;
  const int m = L & 15, quad = L >> 4;
  const int pairI = blockIdx.x;      // 0..15
  const int h = blockIdx.y, b = blockIdx.z;
  const size_t tb = (size_t)b * 2048;
  const size_t hbase = (size_t)h * 4096;
  u16* pw = &pS[w * (16 * 136)];

  // staging index decomposition (256 threads, 4 chunks each)
  const int krow[4] = { (0*256+tid) >> 3, (1*256+tid) >> 3, (2*256+tid) >> 3, (3*256+tid) >> 3 };
  const int kc   = tid & 7;
  const int vf[4]  = { (0*256+tid) >> 4, (1*256+tid) >> 4, (2*256+tid) >> 4, (3*256+tid) >> 4 };
  const int vc   = tid & 15;

  for (int seg = 0; seg < 2; seg++) {
    const int qt = seg ? (31 - pairI) : pairI;
    const int q0 = qt << 6;
    const u16* qp = qh + ((hbase + tb + q0 + w * 16 + m) << 6) + quad * 8;
    const bf16x8 aq0 = *(const bf16x8*)qp;
    const bf16x8 aq1 = *(const bf16x8*)(qp + 32);

    f32x4 zero4 = {0.f, 0.f, 0.f, 0.f};
    f32x4 O[4];
#pragma unroll
    for (int fb = 0; fb < 4; fb++) O[fb] = zero4;
    float mrow[4] = {-30000.f, -30000.f, -30000.f, -30000.f};
    float lrow[4] = {0.f, 0.f, 0.f, 0.f};

    const int nj = (q0 >> 7) + 1;
    int4 kr[4], vr[4];
    // preload k-step 0
#pragma unroll
    for (int i = 0; i < 4; i++) {
      kr[i] = *(const int4*)(kh + ((hbase + tb + krow[i]) << 6) + kc * 8);
      vr[i] = *(const int4*)(vT + (((size_t)h * 64 + vf[i]) << 12) + tb + vc * 8);
    }

    for (int j = 0; j < nj; j++) {
      const int k0 = j << 7;
      __syncthreads();   // prev-iter LDS reads done
#pragma unroll
      for (int i = 0; i < 4; i++) {
        *(int4*)&kS[krow[i] * 72 + kc * 8] = kr[i];
        *(int4*)&vS[vf[i] * 136 + vc * 8] = vr[i];
      }
      __syncthreads();
      if (j + 1 < nj) {
        const int k1 = (j + 1) << 7;
#pragma unroll
        for (int i = 0; i < 4; i++) {
          kr[i] = *(const int4*)(kh + ((hbase + tb + k1 + krow[i]) << 6) + kc * 8);
          vr[i] = *(const int4*)(vT + (((size_t)h * 64 + vf[i]) << 12) + tb + k1 + vc * 8);
        }
      }
      // S = Q K^T : 16 rows x 128 cols per wave
      f32x4 sc[8];
#pragma unroll
      for (int cb = 0; cb < 8; cb++) {
        const int kb = (cb * 16 + m) * 72;
        bf16x8 k0f = *(const bf16x8*)&kS[kb + quad * 8];
        bf16x8 k1f = *(const bf16x8*)&kS[kb + 32 + quad * 8];
        f32x4 t = zero4;
        t = __builtin_amdgcn_mfma_f32_16x16x32_bf16(aq0, k0f, t, 0, 0, 0);
        t = __builtin_amdgcn_mfma_f32_16x16x32_bf16(aq1, k1f, t, 0, 0, 0);
        sc[cb] = t;
      }
      if (k0 + 128 > q0) {   // tile touches the diagonal: causal mask
#pragma unroll
        for (int cb = 0; cb < 8; cb++)
#pragma unroll
          for (int r = 0; r < 4; r++) {
            int rowg = q0 + w * 16 + quad * 4 + r;
            int colg = k0 + cb * 16 + m;
            if (colg > rowg) sc[cb][r] = -30000.f;
          }
      }
      // online softmax (row groups = 16 lanes)
#pragma unroll
      for (int r = 0; r < 4; r++) {
        float mx = sc[0][r];
#pragma unroll
        for (int cb = 1; cb < 8; cb++) mx = fmaxf(mx, sc[cb][r]);
        mx = fmaxf(mx, __shfl_xor(mx, 1, 64));
        mx = fmaxf(mx, __shfl_xor(mx, 2, 64));
        mx = fmaxf(mx, __shfl_xor(mx, 4, 64));
        mx = fmaxf(mx, __shfl_xor(mx, 8, 64));
        float mnew = fmaxf(mrow[r], mx);
        float alpha = __builtin_amdgcn_exp2f(mrow[r] - mnew);
        float sum = 0.f;
#pragma unroll
        for (int cb = 0; cb < 8; cb++) {
          float pv = __builtin_amdgcn_exp2f(sc[cb][r] - mnew);
          sc[cb][r] = pv; sum += pv;
        }
        sum += __shfl_xor(sum, 1, 64);
        sum += __shfl_xor(sum, 2, 64);
        sum += __shfl_xor(sum, 4, 64);
        sum += __shfl_xor(sum, 8, 64);
        lrow[r] = lrow[r] * alpha + sum;
        mrow[r] = mnew;
#pragma unroll
        for (int fb = 0; fb < 4; fb++) O[fb][r] *= alpha;
      }
      // P: C-layout -> per-wave LDS -> A-layout (no barrier: same wave)
#pragma unroll
      for (int cb = 0; cb < 8; cb++)
#pragma unroll
        for (int r = 0; r < 4; r++)
          pw[(quad * 4 + r) * 136 + cb * 16 + m] = f2bf(sc[cb][r]);
      bf16x8 ap[4];
#pragma unroll
      for (int kk = 0; kk < 4; kk++)
        ap[kk] = *(const bf16x8*)&pw[m * 136 + kk * 32 + quad * 8];
#pragma unroll
      for (int fb = 0; fb < 4; fb++) {
        const int vb = (fb * 16 + m) * 136;
#pragma unroll
        for (int kk = 0; kk < 4; kk++) {
          bf16x8 bv = *(const bf16x8*)&vS[vb + kk * 32 + quad * 8];
          O[fb] = __builtin_amdgcn_mfma_f32_16x16x32_bf16(ap[kk], bv, O[fb], 0, 0, 0);
        }
      }
    }
    // write z (token-major), normalize
    float inv[4];
#pragma unroll
    for (int r = 0; r < 4; r++) inv[r] = 1.f / lrow[r];
#pragma unroll
    for (int fb = 0; fb < 4; fb++)
#pragma unroll
      for (int r = 0; r < 4; r++) {
        size_t tok = tb + q0 + w * 16 + quad * 4 + r;
        z[tok * 1024 + h * 64 + fb * 16 + m] = f2bf(O[fb][r] * inv[r]);
      }
    __syncthreads();   // all waves done before next segment re-stages
  }
}

// ---------------------------------------------------------------------------
extern "C" void kernel_launch(void* const* d_in, const int* in_sizes, int n_in,
                              void* d_out, int out_size, void* d_ws, size_t ws_size,
                              hipStream_t stream) {
  (void)in_sizes; (void)n_in; (void)out_size; (void)ws_size;
  const void* resid_pre = d_in[0];
  const void* ln1_w = d_in[1];
  const void* ln1_b = d_in[2];
  const void* W_Q   = d_in[3];
  const void* b_Q   = d_in[4];
  const void* W_K   = d_in[5];
  const void* b_K   = d_in[6];
  const void* W_V   = d_in[7];
  const void* b_V   = d_in[8];
  const void* W_O   = d_in[9];
  const void* b_O   = d_in[10];
  const void* ln2_w = d_in[11];
  const void* ln2_b = d_in[12];
  const void* W_in  = d_in[13];
  const void* b_in  = d_in[14];
  const void* W_out = d_in[15];
  const void* b_out = d_in[16];

  char* p = (char*)d_ws;
  auto alloc = [&](size_t bytes) {
    char* r = p; p += (bytes + 255) & ~(size_t)255; return (void*)r;
  };
  int*   flag      = (int*)  alloc(256);
  u16*   WqkvT     = (u16*)  alloc(3072ull * 1024 * 2);
  u16*   WoT       = (u16*)  alloc(1024ull * 1024 * 2);
  u16*   WinT      = (u16*)  alloc(4096ull * 1024 * 2);
  u16*   WoutT     = (u16*)  alloc(1024ull * 4096 * 2);
  float* biases    = (float*)alloc(9216 * 4);
  u16*   xn        = (u16*)  alloc(4096ull * 1024 * 2);  // reused as z
  u16*   q_hm      = (u16*)  alloc(16ull * 4096 * 64 * 2);
  u16*   k_hm      = (u16*)  alloc(16ull * 4096 * 64 * 2);
  u16*   vTws      = (u16*)  alloc(16ull * 64 * 4096 * 2);
  float* resid_mid = (float*)alloc(4096ull * 1024 * 4);
  u16*   h2        = (u16*)  alloc(4096ull * 1024 * 2);
  u16*   act       = (u16*)  alloc(4096ull * 4096 * 2);
  u16*   z = xn;

  detect_dtype<<<1, 256, 0, stream>>>((const unsigned int*)resid_pre, flag);

  pack_qkvT<<<3072 * 1024 / 256, 256, 0, stream>>>(flag, W_Q, W_K, W_V, WqkvT);
  transpose_any<<<1024 * 1024 / 256, 256, 0, stream>>>(flag, W_O,   WoT,   10, 1024);
  transpose_any<<<1024 * 4096 / 256, 256, 0, stream>>>(flag, W_in,  WinT,  10, 4096);
  transpose_any<<<4096 * 1024 / 256, 256, 0, stream>>>(flag, W_out, WoutT, 12, 1024);
  pack_biases<<<36, 256, 0, stream>>>(flag, b_Q, b_K, b_V, b_O, b_in, b_out, biases);

  ln_fwd<0><<<4096, 256, 0, stream>>>(flag, resid_pre, ln1_w, ln1_b, xn);
  // qkv -> head-major q/k + transposed v
  gemm_bt<4><<<dim3(3072 / 128, 4096 / 128), 256, 0, stream>>>(
      flag, xn, WqkvT, biases, nullptr, q_hm, k_hm, vTws, 4096, 3072, 1024);
  // balanced causal flash attention -> z
  attn_fwd<<<dim3(16, 16, 2), 256, 0, stream>>>(q_hm, k_hm, vTws, z);
  // resid_mid = resid_pre + z @ W_O + b_O   (fp32)
  gemm_bt<2><<<dim3(1024 / 128, 4096 / 128), 256, 0, stream>>>(
      flag, z, WoT, biases + 3072, resid_pre, resid_mid, nullptr, nullptr, 4096, 1024, 1024);
  ln_fwd<1><<<4096, 256, 0, stream>>>(flag, resid_mid, ln2_w, ln2_b, h2);
  // act = relu(h2 @ W_in + b_in)
  gemm_bt<1><<<dim3(4096 / 128, 4096 / 128), 256, 0, stream>>>(
      flag, h2, WinT, biases + 4096, nullptr, act, nullptr, nullptr, 4096, 4096, 1024);
  // out = resid_mid + act @ W_out + b_out
  gemm_bt<3><<<dim3(1024 / 128, 4096 / 128), 256, 0, stream>>>(
      flag, act, WoutT, biases + 8192, resid_mid, d_out, nullptr, nullptr, 4096, 1024, 4096);
}

// Round 4
// 542.258 us; speedup vs baseline: 1.2452x; 1.0257x over previous
//
#include <hip/hip_runtime.h>
#include <stdint.h>

// ---------------------------------------------------------------------------
// TransformerBlock on MI355X (gfx950). Runtime dtype detection (fp32 vs bf16
// inputs), bf16-MFMA internal compute, fp32 accumulation + fp32 residual path.
// B=2 S=2048 D=1024 H=16 K=64 MLP=4096; tokens M = 4096.
// R4: LDS-tiled weight transposes (was 16x fetch amplification); attention
// merges the paired q-tiles into one KV pass + XCD-swizzled grid for L2 reuse.
// ---------------------------------------------------------------------------

typedef unsigned short u16;
typedef __bf16 bf16x8 __attribute__((ext_vector_type(8)));
typedef float  f32x4  __attribute__((ext_vector_type(4)));

#define QSCALE 0.18033688011112042f   // (1/sqrt(64)) * log2(e): softmax via exp2

__device__ __forceinline__ float bf2f(unsigned int u) {
  union { unsigned int u; float f; } v; v.u = u << 16; return v.f;
}
__device__ __forceinline__ u16 f2bf(float f) {
  union { float f; unsigned int u; } v; v.f = f;
  unsigned int r = v.u + 0x7FFFu + ((v.u >> 16) & 1u);   // RNE
  return (u16)(r >> 16);
}
__device__ __forceinline__ float loadf(const void* p, size_t i, int isf) {
  return isf ? ((const float*)p)[i] : bf2f(((const u16*)p)[i]);
}

typedef const __attribute__((address_space(1))) void* gas_t;
typedef __attribute__((address_space(3))) void* las_t;
__device__ __forceinline__ void gl_lds16(const u16* g, u16* l) {
  __builtin_amdgcn_global_load_lds((gas_t)g, (las_t)l, 16, 0, 0);
}

// ---------------------------------------------------------------------------
__global__ __launch_bounds__(256) void detect_dtype(
    const unsigned int* __restrict__ x, int* __restrict__ flag) {
  __shared__ int cnt;
  if (threadIdx.x == 0) cnt = 0;
  __syncthreads();
  int c = 0;
  for (int i = threadIdx.x; i < 512; i += 256) {
    unsigned int e = (x[i] >> 23) & 0xFFu;
    if (e >= 97u && e <= 157u) c++;
  }
  atomicAdd(&cnt, c);
  __syncthreads();
  if (threadIdx.x == 0) *flag = (cnt > 384) ? 1 : 0;
}

// ---------------------------------------------------------------------------
// Tiled transposes: 64x64 tiles through LDS (stride-65 pad -> 2-way = free).
// Both global sides fully coalesced.
// ---------------------------------------------------------------------------
// W_Q/W_K/W_V [h][1024][64] -> WT[mat*1024 + h*64 + k][1024]; Q scaled.
__global__ __launch_bounds__(256) void pack_qkv_tiled(
    const int* __restrict__ flagp,
    const void* __restrict__ Wq, const void* __restrict__ Wk, const void* __restrict__ Wv,
    u16* __restrict__ WT) {
  __shared__ float t[64][65];
  const int isf = *flagp;
  const int tid = threadIdx.x;
  const int mh = blockIdx.y;            // mat*16 + h
  const int mat = mh >> 4, h = mh & 15;
  const int d0 = blockIdx.x << 6;       // d-tile
  const void* src = (mat == 0) ? Wq : (mat == 1) ? Wk : Wv;
  const float scale = (mat == 0) ? QSCALE : 1.f;
  const int lane = tid & 63, rr = tid >> 6;
  const size_t sbase = ((size_t)h << 16) + lane;
#pragma unroll
  for (int i = 0; i < 16; i++) {
    int d = i * 4 + rr;
    t[d][lane] = loadf(src, sbase + (size_t)(d0 + d) * 64, isf) * scale;
  }
  __syncthreads();
#pragma unroll
  for (int i = 0; i < 16; i++) {
    int k = i * 4 + rr;
    WT[((size_t)((mat << 10) + (h << 6) + k) << 10) + d0 + lane] = f2bf(t[lane][k]);
  }
}

// generic: src [R][C] (flag dtype) -> dst [C][R] bf16
__global__ __launch_bounds__(256) void transpose_tiled(
    const int* __restrict__ flagp, const void* __restrict__ src,
    u16* __restrict__ dst, int R, int C) {
  __shared__ float t[64][65];
  const int isf = *flagp;
  const int tid = threadIdx.x;
  const int c0 = blockIdx.x << 6, r0 = blockIdx.y << 6;
  const int lane = tid & 63, rr = tid >> 6;
#pragma unroll
  for (int i = 0; i < 16; i++) {
    int r = i * 4 + rr;
    t[r][lane] = loadf(src, (size_t)(r0 + r) * C + c0 + lane, isf);
  }
  __syncthreads();
#pragma unroll
  for (int i = 0; i < 16; i++) {
    int c = i * 4 + rr;
    dst[(size_t)(c0 + c) * R + r0 + lane] = f2bf(t[lane][c]);
  }
}

__global__ __launch_bounds__(256) void pack_biases(
    const int* __restrict__ flagp,
    const void* bq, const void* bk, const void* bv,
    const void* bO, const void* bin, const void* bout,
    float* __restrict__ out) {
  const int isf = *flagp;
  int i = blockIdx.x * 256 + threadIdx.x;
  float v;
  if (i < 1024)      v = loadf(bq,   i,        isf) * QSCALE;
  else if (i < 2048) v = loadf(bk,   i - 1024, isf);
  else if (i < 3072) v = loadf(bv,   i - 2048, isf);
  else if (i < 4096) v = loadf(bO,   i - 3072, isf);
  else if (i < 8192) v = loadf(bin,  i - 4096, isf);
  else               v = loadf(bout, i - 8192, isf);
  out[i] = v;
}

// ---------------------------------------------------------------------------
template<int SRC>
__global__ __launch_bounds__(256) void ln_fwd(
    const int* __restrict__ flagp, const void* __restrict__ xin,
    const void* __restrict__ w, const void* __restrict__ b,
    u16* __restrict__ out) {
  const int isf = *flagp;
  const int row = blockIdx.x, tid = threadIdx.x;
  const int col = tid << 2;
  const size_t base = ((size_t)row << 10) + col;
  float v[4];
#pragma unroll
  for (int i = 0; i < 4; i++)
    v[i] = (SRC == 1) ? ((const float*)xin)[base + i] : loadf(xin, base + i, isf);
  float s  = v[0] + v[1] + v[2] + v[3];
  float ss = v[0]*v[0] + v[1]*v[1] + v[2]*v[2] + v[3]*v[3];
#pragma unroll
  for (int mk = 32; mk >= 1; mk >>= 1) {
    s  += __shfl_xor(s,  mk, 64);
    ss += __shfl_xor(ss, mk, 64);
  }
  __shared__ float red[8];
  if ((tid & 63) == 0) { red[tid >> 6] = s; red[4 + (tid >> 6)] = ss; }
  __syncthreads();
  float S  = red[0] + red[1] + red[2] + red[3];
  float SS = red[4] + red[5] + red[6] + red[7];
  float mean = S * (1.f / 1024.f);
  float var  = SS * (1.f / 1024.f) - mean * mean;
  float rstd = rsqrtf(var + 1e-5f);
  u16 e[4];
#pragma unroll
  for (int i = 0; i < 4; i++) {
    float wv = loadf(w, col + i, isf);
    float bv = loadf(b, col + i, isf);
    e[i] = f2bf((v[i] - mean) * rstd * wv + bv);
  }
  uint2 o;
  o.x = (unsigned)e[0] | ((unsigned)e[1] << 16);
  o.y = (unsigned)e[2] | ((unsigned)e[3] << 16);
  *(uint2*)(out + base) = o;
}

// ---------------------------------------------------------------------------
// GEMM C[M,N] = A[M,K] @ BT[N,K]^T + bias, m97 structure.
// MODE 0: bf16 out; 1: relu+bf16; 2: +flagged resid -> fp32 out;
// MODE 3: +fp32 resid -> flagged out (d_out)
// MODE 4: QKV epilogue -> q_hm[h][t][64] (out), k_hm (out2), vT[h][f][4096] (out3)
// ---------------------------------------------------------------------------
template<int MODE>
__global__ __launch_bounds__(256) void gemm_bt(
    const int* __restrict__ flagp,
    const u16* __restrict__ A, const u16* __restrict__ BT,
    const float* __restrict__ bias, const void* __restrict__ resid,
    void* __restrict__ out, void* __restrict__ out2, void* __restrict__ out3,
    int M, int N, int K) {
  __shared__ u16 as[128 * 32];
  __shared__ u16 bs[128 * 32];
  int isf = 0;
  if (MODE == 2 || MODE == 3) isf = *flagp;
  const int tid = threadIdx.x;
  const int L = tid & 63, w = tid >> 6;
  const int wm = (w >> 1) << 6, wn = (w & 1) << 6;
  const int row0 = blockIdx.y << 7, col0 = blockIdx.x << 7;
  const int m = L & 15, quad = L >> 4;

  f32x4 zero4 = {0.f, 0.f, 0.f, 0.f};
  f32x4 acc[4][4];
#pragma unroll
  for (int i = 0; i < 4; i++)
#pragma unroll
    for (int j = 0; j < 4; j++) acc[i][j] = zero4;

  const int tm = tid >> 2;
  const int tk = (tid & 3) << 3;
  const u16* Ag  = A  + (size_t)(row0 + tm) * K + tk;
  const u16* Ag2 = Ag + (size_t)64 * K;
  const u16* Bg  = BT + (size_t)(col0 + tm) * K + tk;
  const u16* Bg2 = Bg + (size_t)64 * K;
  u16* asl  = &as[tid * 8];
  u16* asl2 = &as[2048 + tid * 8];
  u16* bsl  = &bs[tid * 8];
  u16* bsl2 = &bs[2048 + tid * 8];

  const int aoff = (wm + m) * 32 + quad * 8;
  const int boff = (wn + m) * 32 + quad * 8;

  for (int kk = 0; kk < K; kk += 32) {
    __syncthreads();
    gl_lds16(Ag  + kk, asl);
    gl_lds16(Ag2 + kk, asl2);
    gl_lds16(Bg  + kk, bsl);
    gl_lds16(Bg2 + kk, bsl2);
    __syncthreads();
    bf16x8 af[4], bfr[4];
#pragma unroll
    for (int i = 0; i < 4; i++) af[i]  = *(const bf16x8*)&as[aoff + i * (16 * 32)];
#pragma unroll
    for (int j = 0; j < 4; j++) bfr[j] = *(const bf16x8*)&bs[boff + j * (16 * 32)];
#pragma unroll
    for (int i = 0; i < 4; i++)
#pragma unroll
      for (int j = 0; j < 4; j++)
        acc[i][j] = __builtin_amdgcn_mfma_f32_16x16x32_bf16(af[i], bfr[j], acc[i][j], 0, 0, 0);
  }

#pragma unroll
  for (int j = 0; j < 4; j++) {
    const int col = col0 + wn + j * 16 + m;
    const float bval = bias[col];
    if (MODE == 4) {
      const int sel = col >> 10;
      const int hh  = (col >> 6) & 15;
      const int f   = col & 63;
#pragma unroll
      for (int i = 0; i < 4; i++) {
        const int rowb = row0 + wm + i * 16 + quad * 4;
        if (sel < 2) {
          u16* dst = (u16*)(sel ? out2 : out);
#pragma unroll
          for (int r = 0; r < 4; r++)
            dst[((((size_t)hh << 12) + rowb + r) << 6) + f] = f2bf(acc[i][j][r] + bval);
        } else {
          u16 e[4];
#pragma unroll
          for (int r = 0; r < 4; r++) e[r] = f2bf(acc[i][j][r] + bval);
          uint2 o;
          o.x = (unsigned)e[0] | ((unsigned)e[1] << 16);
          o.y = (unsigned)e[2] | ((unsigned)e[3] << 16);
          *(uint2*)&((u16*)out3)[(((size_t)hh * 64 + f) << 12) + rowb] = o;
        }
      }
    } else {
#pragma unroll
      for (int i = 0; i < 4; i++) {
        const int rowb = row0 + wm + i * 16 + quad * 4;
#pragma unroll
        for (int r = 0; r < 4; r++) {
          float vv = acc[i][j][r] + bval;
          size_t idx = (size_t)(rowb + r) * N + col;
          if (MODE == 0) {
            ((u16*)out)[idx] = f2bf(vv);
          } else if (MODE == 1) {
            ((u16*)out)[idx] = f2bf(fmaxf(vv, 0.f));
          } else if (MODE == 2) {
            ((float*)out)[idx] = vv + loadf(resid, idx, isf);
          } else if (MODE == 3) {
            float o = vv + ((const float*)resid)[idx];
            if (isf) ((float*)out)[idx] = o;
            else     ((u16*)out)[idx]   = f2bf(o);
          }
        }
      }
    }
  }
}

// ---------------------------------------------------------------------------
// Flash attention, causal, balanced + merged KV pass. Block = 4 waves;
// processes q-tiles (pairI, 31-pairI) simultaneously against ONE KV stream.
// Grid (32,16,1): x = h*2+b (fast dim -> same (h,b) pair-blocks share XCD),
// y = pairI. k-step 128. qh/kh [h][4096][64] (Q pre-scaled), vT [h][64][4096].
// ---------------------------------------------------------------------------
__global__ __launch_bounds__(256) void attn_fwd(
    const u16* __restrict__ qh, const u16* __restrict__ kh,
    const u16* __restrict__ vT, u16* __restrict__ z) {
  __shared__ u16 kS[128 * 72];       // K tile [tok][64+8 pad]
  __shared__ u16 vS[64 * 136];       // V^T tile [f][128+8 pad]
  __shared__ u16 pS[4 * 16 * 136];   // per-wave P [16][128+8 pad]
  const int tid = threadIdx.x, L = tid & 63, w = tid >> 6;
  const int m = L & 15, quad = L >> 4;
  const int combo = blockIdx.x;      // h*2 + b
  const int pairI = blockIdx.y;      // 0..15
  const int h = combo >> 1, b = combo & 1;
  const size_t tb = (size_t)b * 2048;
  const size_t hbase = (size_t)h * 4096;
  u16* pw = &pS[w * (16 * 136)];

  const int q0A = pairI << 6, q0B = (31 - pairI) << 6;
  const int njA = (q0A >> 7) + 1, njB = (q0B >> 7) + 1;

  const u16* qpA = qh + ((hbase + tb + q0A + w * 16 + m) << 6) + quad * 8;
  const u16* qpB = qh + ((hbase + tb + q0B + w * 16 + m) << 6) + quad * 8;
  const bf16x8 aqA0 = *(const bf16x8*)qpA;
  const bf16x8 aqA1 = *(const bf16x8*)(qpA + 32);
  const bf16x8 aqB0 = *(const bf16x8*)qpB;
  const bf16x8 aqB1 = *(const bf16x8*)(qpB + 32);

  f32x4 zero4 = {0.f, 0.f, 0.f, 0.f};
  f32x4 OA[4], OB[4];
#pragma unroll
  for (int fb = 0; fb < 4; fb++) { OA[fb] = zero4; OB[fb] = zero4; }
  float mA[4], lA[4], mB[4], lB[4];
#pragma unroll
  for (int r = 0; r < 4; r++) { mA[r] = -30000.f; lA[r] = 0.f; mB[r] = -30000.f; lB[r] = 0.f; }

  const int krow[4] = { (0*256+tid) >> 3, (1*256+tid) >> 3, (2*256+tid) >> 3, (3*256+tid) >> 3 };
  const int kc = tid & 7;
  const int vf[4] = { (0*256+tid) >> 4, (1*256+tid) >> 4, (2*256+tid) >> 4, (3*256+tid) >> 4 };
  const int vc = tid & 15;

  auto seg = [&](const bf16x8& a0, const bf16x8& a1, f32x4* O,
                 float* mrow, float* lrow, int q0, int k0) {
    f32x4 sc[8];
#pragma unroll
    for (int cb = 0; cb < 8; cb++) {
      const int kb = (cb * 16 + m) * 72;
      bf16x8 k0f = *(const bf16x8*)&kS[kb + quad * 8];
      bf16x8 k1f = *(const bf16x8*)&kS[kb + 32 + quad * 8];
      f32x4 t = zero4;
      t = __builtin_amdgcn_mfma_f32_16x16x32_bf16(a0, k0f, t, 0, 0, 0);
      t = __builtin_amdgcn_mfma_f32_16x16x32_bf16(a1, k1f, t, 0, 0, 0);
      sc[cb] = t;
    }
    if (k0 + 128 > q0) {
#pragma unroll
      for (int cb = 0; cb < 8; cb++)
#pragma unroll
        for (int r = 0; r < 4; r++) {
          int rowg = q0 + w * 16 + quad * 4 + r;
          int colg = k0 + cb * 16 + m;
          if (colg > rowg) sc[cb][r] = -30000.f;
        }
    }
#pragma unroll
    for (int r = 0; r < 4; r++) {
      float mx = sc[0][r];
#pragma unroll
      for (int cb = 1; cb < 8; cb++) mx = fmaxf(mx, sc[cb][r]);
      mx = fmaxf(mx, __shfl_xor(mx, 1, 64));
      mx = fmaxf(mx, __shfl_xor(mx, 2, 64));
      mx = fmaxf(mx, __shfl_xor(mx, 4, 64));
      mx = fmaxf(mx, __shfl_xor(mx, 8, 64));
      float mnew = fmaxf(mrow[r], mx);
      float alpha = __builtin_amdgcn_exp2f(mrow[r] - mnew);
      float sum = 0.f;
#pragma unroll
      for (int cb = 0; cb < 8; cb++) {
        float pv = __builtin_amdgcn_exp2f(sc[cb][r] - mnew);
        sc[cb][r] = pv; sum += pv;
      }
      sum += __shfl_xor(sum, 1, 64);
      sum += __shfl_xor(sum, 2, 64);
      sum += __shfl_xor(sum, 4, 64);
      sum += __shfl_xor(sum, 8, 64);
      lrow[r] = lrow[r] * alpha + sum;
      mrow[r] = mnew;
#pragma unroll
      for (int fb = 0; fb < 4; fb++) O[fb][r] *= alpha;
    }
#pragma unroll
    for (int cb = 0; cb < 8; cb++)
#pragma unroll
      for (int r = 0; r < 4; r++)
        pw[(quad * 4 + r) * 136 + cb * 16 + m] = f2bf(sc[cb][r]);
    bf16x8 ap[4];
#pragma unroll
    for (int kk = 0; kk < 4; kk++)
      ap[kk] = *(const bf16x8*)&pw[m * 136 + kk * 32 + quad * 8];
#pragma unroll
    for (int fb = 0; fb < 4; fb++) {
      const int vb = (fb * 16 + m) * 136;
#pragma unroll
      for (int kk = 0; kk < 4; kk++) {
        bf16x8 bv = *(const bf16x8*)&vS[vb + kk * 32 + quad * 8];
        O[fb] = __builtin_amdgcn_mfma_f32_16x16x32_bf16(ap[kk], bv, O[fb], 0, 0, 0);
      }
    }
  };

  int4 kr[4], vr[4];
#pragma unroll
  for (int i = 0; i < 4; i++) {
    kr[i] = *(const int4*)(kh + ((hbase + tb + krow[i]) << 6) + kc * 8);
    vr[i] = *(const int4*)(vT + (((size_t)h * 64 + vf[i]) << 12) + tb + vc * 8);
  }

  for (int j = 0; j < njB; j++) {
    const int k0 = j << 7;
    __syncthreads();
#pragma unroll
    for (int i = 0; i < 4; i++) {
      *(int4*)&kS[krow[i] * 72 + kc * 8] = kr[i];
      *(int4*)&vS[vf[i] * 136 + vc * 8] = vr[i];
    }
    __syncthreads();
    if (j + 1 < njB) {
      const int k1 = (j + 1) << 7;
#pragma unroll
      for (int i = 0; i < 4; i++) {
        kr[i] = *(const int4*)(kh + ((hbase + tb + k1 + krow[i]) << 6) + kc * 8);
        vr[i] = *(const int4*)(vT + (((size_t)h * 64 + vf[i]) << 12) + tb + k1 + vc * 8);
      }
    }
    seg(aqB0, aqB1, OB, mB, lB, q0B, k0);
    if (j < njA) seg(aqA0, aqA1, OA, mA, lA, q0A, k0);
  }

  float invA[4], invB[4];
#pragma unroll
  for (int r = 0; r < 4; r++) { invA[r] = 1.f / lA[r]; invB[r] = 1.f / lB[r]; }
#pragma unroll
  for (int fb = 0; fb < 4; fb++)
#pragma unroll
    for (int r = 0; r < 4; r++) {
      size_t tokA = tb + q0A + w * 16 + quad * 4 + r;
      size_t tokB = tb + q0B + w * 16 + quad * 4 + r;
      z[tokA * 1024 + h * 64 + fb * 16 + m] = f2bf(OA[fb][r] * invA[r]);
      z[tokB * 1024 + h * 64 + fb * 16 + m] = f2bf(OB[fb][r] * invB[r]);
    }
}

// ---------------------------------------------------------------------------
extern "C" void kernel_launch(void* const* d_in, const int* in_sizes, int n_in,
                              void* d_out, int out_size, void* d_ws, size_t ws_size,
                              hipStream_t stream) {
  (void)in_sizes; (void)n_in; (void)out_size; (void)ws_size;
  const void* resid_pre = d_in[0];
  const void* ln1_w = d_in[1];
  const void* ln1_b = d_in[2];
  const void* W_Q   = d_in[3];
  const void* b_Q   = d_in[4];
  const void* W_K   = d_in[5];
  const void* b_K   = d_in[6];
  const void* W_V   = d_in[7];
  const void* b_V   = d_in[8];
  const void* W_O   = d_in[9];
  const void* b_O   = d_in[10];
  const void* ln2_w = d_in[11];
  const void* ln2_b = d_in[12];
  const void* W_in  = d_in[13];
  const void* b_in  = d_in[14];
  const void* W_out = d_in[15];
  const void* b_out = d_in[16];

  char* p = (char*)d_ws;
  auto alloc = [&](size_t bytes) {
    char* r = p; p += (bytes + 255) & ~(size_t)255; return (void*)r;
  };
  int*   flag      = (int*)  alloc(256);
  u16*   WqkvT     = (u16*)  alloc(3072ull * 1024 * 2);
  u16*   WoT       = (u16*)  alloc(1024ull * 1024 * 2);
  u16*   WinT      = (u16*)  alloc(4096ull * 1024 * 2);
  u16*   WoutT     = (u16*)  alloc(1024ull * 4096 * 2);
  float* biases    = (float*)alloc(9216 * 4);
  u16*   xn        = (u16*)  alloc(4096ull * 1024 * 2);  // reused as z
  u16*   q_hm      = (u16*)  alloc(16ull * 4096 * 64 * 2);
  u16*   k_hm      = (u16*)  alloc(16ull * 4096 * 64 * 2);
  u16*   vTws      = (u16*)  alloc(16ull * 64 * 4096 * 2);
  float* resid_mid = (float*)alloc(4096ull * 1024 * 4);
  u16*   h2        = (u16*)  alloc(4096ull * 1024 * 2);
  u16*   act       = (u16*)  alloc(4096ull * 4096 * 2);
  u16*   z = xn;

  detect_dtype<<<1, 256, 0, stream>>>((const unsigned int*)resid_pre, flag);

  // tiled weight packs (coalesced both sides)
  pack_qkv_tiled<<<dim3(16, 48), 256, 0, stream>>>(flag, W_Q, W_K, W_V, WqkvT);
  transpose_tiled<<<dim3(16, 16), 256, 0, stream>>>(flag, W_O,   WoT,   1024, 1024);
  transpose_tiled<<<dim3(64, 16), 256, 0, stream>>>(flag, W_in,  WinT,  1024, 4096);
  transpose_tiled<<<dim3(16, 64), 256, 0, stream>>>(flag, W_out, WoutT, 4096, 1024);
  pack_biases<<<36, 256, 0, stream>>>(flag, b_Q, b_K, b_V, b_O, b_in, b_out, biases);

  ln_fwd<0><<<4096, 256, 0, stream>>>(flag, resid_pre, ln1_w, ln1_b, xn);
  // qkv -> head-major q/k + transposed v
  gemm_bt<4><<<dim3(3072 / 128, 4096 / 128), 256, 0, stream>>>(
      flag, xn, WqkvT, biases, nullptr, q_hm, k_hm, vTws, 4096, 3072, 1024);
  // balanced causal flash attention -> z (merged KV pass, XCD swizzle)
  attn_fwd<<<dim3(32, 16, 1), 256, 0, stream>>>(q_hm, k_hm, vTws, z);
  // resid_mid = resid_pre + z @ W_O + b_O   (fp32)
  gemm_bt<2><<<dim3(1024 / 128, 4096 / 128), 256, 0, stream>>>(
      flag, z, WoT, biases + 3072, resid_pre, resid_mid, nullptr, nullptr, 4096, 1024, 1024);
  ln_fwd<1><<<4096, 256, 0, stream>>>(flag, resid_mid, ln2_w, ln2_b, h2);
  // act = relu(h2 @ W_in + b_in)
  gemm_bt<1><<<dim3(4096 / 128, 4096 / 128), 256, 0, stream>>>(
      flag, h2, WinT, biases + 4096, nullptr, act, nullptr, nullptr, 4096, 4096, 1024);
  // out = resid_mid + act @ W_out + b_out
  gemm_bt<3><<<dim3(1024 / 128, 4096 / 128), 256, 0, stream>>>(
      flag, act, WoutT, biases + 8192, resid_mid, d_out, nullptr, nullptr, 4096, 1024, 4096);
}

// Round 5
// 536.653 us; speedup vs baseline: 1.2582x; 1.0104x over previous
//
#include <hip/hip_runtime.h>
#include <stdint.h>

// ---------------------------------------------------------------------------
// TransformerBlock on MI355X (gfx950). Runtime dtype detection (fp32 vs bf16
// inputs), bf16-MFMA internal compute, fp32 accumulation + fp32 residual path.
// B=2 S=2048 D=1024 H=16 K=64 MLP=4096; tokens M = 4096.
// R5: attention -> flash-decoding split-K (512-token chunks, 2560 blocks,
// <=4 serial k-steps) + merge kernel. Partials live in later-overwritten ws.
// ---------------------------------------------------------------------------

typedef unsigned short u16;
typedef __bf16 bf16x8 __attribute__((ext_vector_type(8)));
typedef float  f32x4  __attribute__((ext_vector_type(4)));

#define QSCALE 0.18033688011112042f   // (1/sqrt(64)) * log2(e): softmax via exp2

__device__ __forceinline__ float bf2f(unsigned int u) {
  union { unsigned int u; float f; } v; v.u = u << 16; return v.f;
}
__device__ __forceinline__ u16 f2bf(float f) {
  union { float f; unsigned int u; } v; v.f = f;
  unsigned int r = v.u + 0x7FFFu + ((v.u >> 16) & 1u);   // RNE
  return (u16)(r >> 16);
}
__device__ __forceinline__ float loadf(const void* p, size_t i, int isf) {
  return isf ? ((const float*)p)[i] : bf2f(((const u16*)p)[i]);
}

typedef const __attribute__((address_space(1))) void* gas_t;
typedef __attribute__((address_space(3))) void* las_t;
__device__ __forceinline__ void gl_lds16(const u16* g, u16* l) {
  __builtin_amdgcn_global_load_lds((gas_t)g, (las_t)l, 16, 0, 0);
}

// ---------------------------------------------------------------------------
__global__ __launch_bounds__(256) void detect_dtype(
    const unsigned int* __restrict__ x, int* __restrict__ flag) {
  __shared__ int cnt;
  if (threadIdx.x == 0) cnt = 0;
  __syncthreads();
  int c = 0;
  for (int i = threadIdx.x; i < 512; i += 256) {
    unsigned int e = (x[i] >> 23) & 0xFFu;
    if (e >= 97u && e <= 157u) c++;
  }
  atomicAdd(&cnt, c);
  __syncthreads();
  if (threadIdx.x == 0) *flag = (cnt > 384) ? 1 : 0;
}

// ---------------------------------------------------------------------------
// Tiled transposes: 64x64 tiles through LDS (stride-65 pad -> 2-way = free).
// ---------------------------------------------------------------------------
__global__ __launch_bounds__(256) void pack_qkv_tiled(
    const int* __restrict__ flagp,
    const void* __restrict__ Wq, const void* __restrict__ Wk, const void* __restrict__ Wv,
    u16* __restrict__ WT) {
  __shared__ float t[64][65];
  const int isf = *flagp;
  const int tid = threadIdx.x;
  const int mh = blockIdx.y;            // mat*16 + h
  const int mat = mh >> 4, h = mh & 15;
  const int d0 = blockIdx.x << 6;       // d-tile
  const void* src = (mat == 0) ? Wq : (mat == 1) ? Wk : Wv;
  const float scale = (mat == 0) ? QSCALE : 1.f;
  const int lane = tid & 63, rr = tid >> 6;
  const size_t sbase = ((size_t)h << 16) + lane;
#pragma unroll
  for (int i = 0; i < 16; i++) {
    int d = i * 4 + rr;
    t[d][lane] = loadf(src, sbase + (size_t)(d0 + d) * 64, isf) * scale;
  }
  __syncthreads();
#pragma unroll
  for (int i = 0; i < 16; i++) {
    int k = i * 4 + rr;
    WT[((size_t)((mat << 10) + (h << 6) + k) << 10) + d0 + lane] = f2bf(t[lane][k]);
  }
}

__global__ __launch_bounds__(256) void transpose_tiled(
    const int* __restrict__ flagp, const void* __restrict__ src,
    u16* __restrict__ dst, int R, int C) {
  __shared__ float t[64][65];
  const int isf = *flagp;
  const int tid = threadIdx.x;
  const int c0 = blockIdx.x << 6, r0 = blockIdx.y << 6;
  const int lane = tid & 63, rr = tid >> 6;
#pragma unroll
  for (int i = 0; i < 16; i++) {
    int r = i * 4 + rr;
    t[r][lane] = loadf(src, (size_t)(r0 + r) * C + c0 + lane, isf);
  }
  __syncthreads();
#pragma unroll
  for (int i = 0; i < 16; i++) {
    int c = i * 4 + rr;
    dst[(size_t)(c0 + c) * R + r0 + lane] = f2bf(t[lane][c]);
  }
}

__global__ __launch_bounds__(256) void pack_biases(
    const int* __restrict__ flagp,
    const void* bq, const void* bk, const void* bv,
    const void* bO, const void* bin, const void* bout,
    float* __restrict__ out) {
  const int isf = *flagp;
  int i = blockIdx.x * 256 + threadIdx.x;
  float v;
  if (i < 1024)      v = loadf(bq,   i,        isf) * QSCALE;
  else if (i < 2048) v = loadf(bk,   i - 1024, isf);
  else if (i < 3072) v = loadf(bv,   i - 2048, isf);
  else if (i < 4096) v = loadf(bO,   i - 3072, isf);
  else if (i < 8192) v = loadf(bin,  i - 4096, isf);
  else               v = loadf(bout, i - 8192, isf);
  out[i] = v;
}

// ---------------------------------------------------------------------------
template<int SRC>
__global__ __launch_bounds__(256) void ln_fwd(
    const int* __restrict__ flagp, const void* __restrict__ xin,
    const void* __restrict__ w, const void* __restrict__ b,
    u16* __restrict__ out) {
  const int isf = *flagp;
  const int row = blockIdx.x, tid = threadIdx.x;
  const int col = tid << 2;
  const size_t base = ((size_t)row << 10) + col;
  float v[4];
#pragma unroll
  for (int i = 0; i < 4; i++)
    v[i] = (SRC == 1) ? ((const float*)xin)[base + i] : loadf(xin, base + i, isf);
  float s  = v[0] + v[1] + v[2] + v[3];
  float ss = v[0]*v[0] + v[1]*v[1] + v[2]*v[2] + v[3]*v[3];
#pragma unroll
  for (int mk = 32; mk >= 1; mk >>= 1) {
    s  += __shfl_xor(s,  mk, 64);
    ss += __shfl_xor(ss, mk, 64);
  }
  __shared__ float red[8];
  if ((tid & 63) == 0) { red[tid >> 6] = s; red[4 + (tid >> 6)] = ss; }
  __syncthreads();
  float S  = red[0] + red[1] + red[2] + red[3];
  float SS = red[4] + red[5] + red[6] + red[7];
  float mean = S * (1.f / 1024.f);
  float var  = SS * (1.f / 1024.f) - mean * mean;
  float rstd = rsqrtf(var + 1e-5f);
  u16 e[4];
#pragma unroll
  for (int i = 0; i < 4; i++) {
    float wv = loadf(w, col + i, isf);
    float bv = loadf(b, col + i, isf);
    e[i] = f2bf((v[i] - mean) * rstd * wv + bv);
  }
  uint2 o;
  o.x = (unsigned)e[0] | ((unsigned)e[1] << 16);
  o.y = (unsigned)e[2] | ((unsigned)e[3] << 16);
  *(uint2*)(out + base) = o;
}

// ---------------------------------------------------------------------------
// GEMM C[M,N] = A[M,K] @ BT[N,K]^T + bias, m97 structure.
// MODE 0: bf16 out; 1: relu+bf16; 2: +flagged resid -> fp32 out;
// MODE 3: +fp32 resid -> flagged out (d_out)
// MODE 4: QKV epilogue -> q_hm[h][t][64] (out), k_hm (out2), vT[h][f][4096] (out3)
// ---------------------------------------------------------------------------
template<int MODE>
__global__ __launch_bounds__(256) void gemm_bt(
    const int* __restrict__ flagp,
    const u16* __restrict__ A, const u16* __restrict__ BT,
    const float* __restrict__ bias, const void* __restrict__ resid,
    void* __restrict__ out, void* __restrict__ out2, void* __restrict__ out3,
    int M, int N, int K) {
  __shared__ u16 as[128 * 32];
  __shared__ u16 bs[128 * 32];
  int isf = 0;
  if (MODE == 2 || MODE == 3) isf = *flagp;
  const int tid = threadIdx.x;
  const int L = tid & 63, w = tid >> 6;
  const int wm = (w >> 1) << 6, wn = (w & 1) << 6;
  const int row0 = blockIdx.y << 7, col0 = blockIdx.x << 7;
  const int m = L & 15, quad = L >> 4;

  f32x4 zero4 = {0.f, 0.f, 0.f, 0.f};
  f32x4 acc[4][4];
#pragma unroll
  for (int i = 0; i < 4; i++)
#pragma unroll
    for (int j = 0; j < 4; j++) acc[i][j] = zero4;

  const int tm = tid >> 2;
  const int tk = (tid & 3) << 3;
  const u16* Ag  = A  + (size_t)(row0 + tm) * K + tk;
  const u16* Ag2 = Ag + (size_t)64 * K;
  const u16* Bg  = BT + (size_t)(col0 + tm) * K + tk;
  const u16* Bg2 = Bg + (size_t)64 * K;
  u16* asl  = &as[tid * 8];
  u16* asl2 = &as[2048 + tid * 8];
  u16* bsl  = &bs[tid * 8];
  u16* bsl2 = &bs[2048 + tid * 8];

  const int aoff = (wm + m) * 32 + quad * 8;
  const int boff = (wn + m) * 32 + quad * 8;

  for (int kk = 0; kk < K; kk += 32) {
    __syncthreads();
    gl_lds16(Ag  + kk, asl);
    gl_lds16(Ag2 + kk, asl2);
    gl_lds16(Bg  + kk, bsl);
    gl_lds16(Bg2 + kk, bsl2);
    __syncthreads();
    bf16x8 af[4], bfr[4];
#pragma unroll
    for (int i = 0; i < 4; i++) af[i]  = *(const bf16x8*)&as[aoff + i * (16 * 32)];
#pragma unroll
    for (int j = 0; j < 4; j++) bfr[j] = *(const bf16x8*)&bs[boff + j * (16 * 32)];
#pragma unroll
    for (int i = 0; i < 4; i++)
#pragma unroll
      for (int j = 0; j < 4; j++)
        acc[i][j] = __builtin_amdgcn_mfma_f32_16x16x32_bf16(af[i], bfr[j], acc[i][j], 0, 0, 0);
  }

#pragma unroll
  for (int j = 0; j < 4; j++) {
    const int col = col0 + wn + j * 16 + m;
    const float bval = bias[col];
    if (MODE == 4) {
      const int sel = col >> 10;
      const int hh  = (col >> 6) & 15;
      const int f   = col & 63;
#pragma unroll
      for (int i = 0; i < 4; i++) {
        const int rowb = row0 + wm + i * 16 + quad * 4;
        if (sel < 2) {
          u16* dst = (u16*)(sel ? out2 : out);
#pragma unroll
          for (int r = 0; r < 4; r++)
            dst[((((size_t)hh << 12) + rowb + r) << 6) + f] = f2bf(acc[i][j][r] + bval);
        } else {
          u16 e[4];
#pragma unroll
          for (int r = 0; r < 4; r++) e[r] = f2bf(acc[i][j][r] + bval);
          uint2 o;
          o.x = (unsigned)e[0] | ((unsigned)e[1] << 16);
          o.y = (unsigned)e[2] | ((unsigned)e[3] << 16);
          *(uint2*)&((u16*)out3)[(((size_t)hh * 64 + f) << 12) + rowb] = o;
        }
      }
    } else {
#pragma unroll
      for (int i = 0; i < 4; i++) {
        const int rowb = row0 + wm + i * 16 + quad * 4;
#pragma unroll
        for (int r = 0; r < 4; r++) {
          float vv = acc[i][j][r] + bval;
          size_t idx = (size_t)(rowb + r) * N + col;
          if (MODE == 0) {
            ((u16*)out)[idx] = f2bf(vv);
          } else if (MODE == 1) {
            ((u16*)out)[idx] = f2bf(fmaxf(vv, 0.f));
          } else if (MODE == 2) {
            ((float*)out)[idx] = vv + loadf(resid, idx, isf);
          } else if (MODE == 3) {
            float o = vv + ((const float*)resid)[idx];
            if (isf) ((float*)out)[idx] = o;
            else     ((u16*)out)[idx]   = f2bf(o);
          }
        }
      }
    }
  }
}

// ---------------------------------------------------------------------------
// Flash attention, split-K (flash-decoding). Block = (combo=h*2+b, qt, ci):
// q-tile of 64 rows vs k-chunk [ci*512, min(ci*512+512, q0+64)). <=4 k-steps
// of 128. Writes unnormalized O (bf16) + per-row (m,l) stats (fp32).
// qh/kh [h][4096][64] (Q pre-scaled), vT [h][64][4096].
// ---------------------------------------------------------------------------
__global__ __launch_bounds__(256) void attn_part(
    const u16* __restrict__ qh, const u16* __restrict__ kh,
    const u16* __restrict__ vT, u16* __restrict__ Opart,
    float* __restrict__ stats) {
  const int combo = blockIdx.x;      // h*2 + b
  const int qt = blockIdx.y;         // 0..31
  const int ci = blockIdx.z;         // 0..3
  const int q0 = qt << 6;
  const int nc = (q0 + 64 + 511) >> 9;
  if (ci >= nc) return;
  const int k_lo = ci << 9;
  const int k_hi = min(k_lo + 512, q0 + 64);
  const int nsteps = (k_hi - k_lo + 127) >> 7;

  __shared__ u16 kS[128 * 72];       // K tile [tok][64+8 pad]
  __shared__ u16 vS[64 * 136];       // V^T tile [f][128+8 pad]
  __shared__ u16 pS[4 * 16 * 136];   // per-wave P [16][128+8 pad]
  const int tid = threadIdx.x, L = tid & 63, w = tid >> 6;
  const int m = L & 15, quad = L >> 4;
  const int h = combo >> 1, b = combo & 1;
  const size_t tb = (size_t)b * 2048;
  const size_t hbase = (size_t)h * 4096;
  u16* pw = &pS[w * (16 * 136)];

  const u16* qp = qh + ((hbase + tb + q0 + w * 16 + m) << 6) + quad * 8;
  const bf16x8 aq0 = *(const bf16x8*)qp;
  const bf16x8 aq1 = *(const bf16x8*)(qp + 32);

  f32x4 zero4 = {0.f, 0.f, 0.f, 0.f};
  f32x4 O[4];
#pragma unroll
  for (int fb = 0; fb < 4; fb++) O[fb] = zero4;
  float mrow[4] = {-30000.f, -30000.f, -30000.f, -30000.f};
  float lrow[4] = {0.f, 0.f, 0.f, 0.f};

  const int krow[4] = { (0*256+tid) >> 3, (1*256+tid) >> 3, (2*256+tid) >> 3, (3*256+tid) >> 3 };
  const int kc = tid & 7;
  const int vf[4] = { (0*256+tid) >> 4, (1*256+tid) >> 4, (2*256+tid) >> 4, (3*256+tid) >> 4 };
  const int vc = tid & 15;

  int4 kr[4], vr[4];
#pragma unroll
  for (int i = 0; i < 4; i++) {
    kr[i] = *(const int4*)(kh + ((hbase + tb + k_lo + krow[i]) << 6) + kc * 8);
    vr[i] = *(const int4*)(vT + (((size_t)h * 64 + vf[i]) << 12) + tb + k_lo + vc * 8);
  }

  for (int j = 0; j < nsteps; j++) {
    const int k0 = k_lo + (j << 7);
    __syncthreads();
#pragma unroll
    for (int i = 0; i < 4; i++) {
      *(int4*)&kS[krow[i] * 72 + kc * 8] = kr[i];
      *(int4*)&vS[vf[i] * 136 + vc * 8] = vr[i];
    }
    __syncthreads();
    if (j + 1 < nsteps) {
      const int k1 = k_lo + ((j + 1) << 7);
#pragma unroll
      for (int i = 0; i < 4; i++) {
        kr[i] = *(const int4*)(kh + ((hbase + tb + k1 + krow[i]) << 6) + kc * 8);
        vr[i] = *(const int4*)(vT + (((size_t)h * 64 + vf[i]) << 12) + tb + k1 + vc * 8);
      }
    }
    // S = Q K^T
    f32x4 sc[8];
#pragma unroll
    for (int cb = 0; cb < 8; cb++) {
      const int kb = (cb * 16 + m) * 72;
      bf16x8 k0f = *(const bf16x8*)&kS[kb + quad * 8];
      bf16x8 k1f = *(const bf16x8*)&kS[kb + 32 + quad * 8];
      f32x4 t = zero4;
      t = __builtin_amdgcn_mfma_f32_16x16x32_bf16(aq0, k0f, t, 0, 0, 0);
      t = __builtin_amdgcn_mfma_f32_16x16x32_bf16(aq1, k1f, t, 0, 0, 0);
      sc[cb] = t;
    }
    if (k0 + 128 > q0) {   // diagonal / tail: causal + range mask
#pragma unroll
      for (int cb = 0; cb < 8; cb++)
#pragma unroll
        for (int r = 0; r < 4; r++) {
          int rowg = q0 + w * 16 + quad * 4 + r;
          int colg = k0 + cb * 16 + m;
          if (colg > rowg) sc[cb][r] = -30000.f;
        }
    }
    // online softmax (row groups = 16 lanes)
#pragma unroll
    for (int r = 0; r < 4; r++) {
      float mx = sc[0][r];
#pragma unroll
      for (int cb = 1; cb < 8; cb++) mx = fmaxf(mx, sc[cb][r]);
      mx = fmaxf(mx, __shfl_xor(mx, 1, 64));
      mx = fmaxf(mx, __shfl_xor(mx, 2, 64));
      mx = fmaxf(mx, __shfl_xor(mx, 4, 64));
      mx = fmaxf(mx, __shfl_xor(mx, 8, 64));
      float mnew = fmaxf(mrow[r], mx);
      float alpha = __builtin_amdgcn_exp2f(mrow[r] - mnew);
      float sum = 0.f;
#pragma unroll
      for (int cb = 0; cb < 8; cb++) {
        float pv = __builtin_amdgcn_exp2f(sc[cb][r] - mnew);
        sc[cb][r] = pv; sum += pv;
      }
      sum += __shfl_xor(sum, 1, 64);
      sum += __shfl_xor(sum, 2, 64);
      sum += __shfl_xor(sum, 4, 64);
      sum += __shfl_xor(sum, 8, 64);
      lrow[r] = lrow[r] * alpha + sum;
      mrow[r] = mnew;
#pragma unroll
      for (int fb = 0; fb < 4; fb++) O[fb][r] *= alpha;
    }
    // P: C-layout -> per-wave LDS -> A-layout (no barrier: same wave)
#pragma unroll
    for (int cb = 0; cb < 8; cb++)
#pragma unroll
      for (int r = 0; r < 4; r++)
        pw[(quad * 4 + r) * 136 + cb * 16 + m] = f2bf(sc[cb][r]);
    bf16x8 ap[4];
#pragma unroll
    for (int kk = 0; kk < 4; kk++)
      ap[kk] = *(const bf16x8*)&pw[m * 136 + kk * 32 + quad * 8];
#pragma unroll
    for (int fb = 0; fb < 4; fb++) {
      const int vb = (fb * 16 + m) * 136;
#pragma unroll
      for (int kk = 0; kk < 4; kk++) {
        bf16x8 bv = *(const bf16x8*)&vS[vb + kk * 32 + quad * 8];
        O[fb] = __builtin_amdgcn_mfma_f32_16x16x32_bf16(ap[kk], bv, O[fb], 0, 0, 0);
      }
    }
  }

  const int slot = (combo * 32 + qt) * 4 + ci;
  u16* op = Opart + ((size_t)slot << 12);
#pragma unroll
  for (int fb = 0; fb < 4; fb++)
#pragma unroll
    for (int r = 0; r < 4; r++) {
      int t = w * 16 + quad * 4 + r;
      op[t * 64 + fb * 16 + m] = f2bf(O[fb][r]);
    }
  if (m == 0) {
#pragma unroll
    for (int r = 0; r < 4; r++) {
      int t = w * 16 + quad * 4 + r;
      stats[slot * 128 + t]      = mrow[r];
      stats[slot * 128 + 64 + t] = lrow[r];
    }
  }
}

// merge partials -> z [t][1024]
__global__ __launch_bounds__(256) void attn_merge(
    const u16* __restrict__ Opart, const float* __restrict__ stats,
    u16* __restrict__ z) {
  const int combo = blockIdx.x, qt = blockIdx.y;
  const int h = combo >> 1, b = combo & 1;
  const int q0 = qt << 6;
  const int nc = (q0 + 64 + 511) >> 9;
  const int tid = threadIdx.x;
  const int t = tid >> 2, f0 = (tid & 3) << 4;
  const int slot0 = (combo * 32 + qt) * 4;
  float M = -3e4f;
  for (int ci = 0; ci < nc; ci++)
    M = fmaxf(M, stats[(slot0 + ci) * 128 + t]);
  float acc[16];
#pragma unroll
  for (int e = 0; e < 16; e++) acc[e] = 0.f;
  float ltot = 0.f;
  for (int ci = 0; ci < nc; ci++) {
    float mi = stats[(slot0 + ci) * 128 + t];
    float li = stats[(slot0 + ci) * 128 + 64 + t];
    float wgt = exp2f(mi - M);
    ltot += wgt * li;
    const u16* op = Opart + (((size_t)(slot0 + ci)) << 12) + t * 64 + f0;
    union { int4 v; u16 u[8]; } a0, a1;
    a0.v = *(const int4*)op;
    a1.v = *(const int4*)(op + 8);
#pragma unroll
    for (int e = 0; e < 8; e++) {
      acc[e]     += wgt * bf2f(a0.u[e]);
      acc[8 + e] += wgt * bf2f(a1.u[e]);
    }
  }
  float inv = 1.f / ltot;
  union { int4 v; u16 u[8]; } o0, o1;
#pragma unroll
  for (int e = 0; e < 8; e++) {
    o0.u[e] = f2bf(acc[e] * inv);
    o1.u[e] = f2bf(acc[8 + e] * inv);
  }
  size_t tok = (size_t)b * 2048 + q0 + t;
  *(int4*)&z[tok * 1024 + h * 64 + f0]     = o0.v;
  *(int4*)&z[tok * 1024 + h * 64 + f0 + 8] = o1.v;
}

// ---------------------------------------------------------------------------
extern "C" void kernel_launch(void* const* d_in, const int* in_sizes, int n_in,
                              void* d_out, int out_size, void* d_ws, size_t ws_size,
                              hipStream_t stream) {
  (void)in_sizes; (void)n_in; (void)out_size; (void)ws_size;
  const void* resid_pre = d_in[0];
  const void* ln1_w = d_in[1];
  const void* ln1_b = d_in[2];
  const void* W_Q   = d_in[3];
  const void* b_Q   = d_in[4];
  const void* W_K   = d_in[5];
  const void* b_K   = d_in[6];
  const void* W_V   = d_in[7];
  const void* b_V   = d_in[8];
  const void* W_O   = d_in[9];
  const void* b_O   = d_in[10];
  const void* ln2_w = d_in[11];
  const void* ln2_b = d_in[12];
  const void* W_in  = d_in[13];
  const void* b_in  = d_in[14];
  const void* W_out = d_in[15];
  const void* b_out = d_in[16];

  char* p = (char*)d_ws;
  auto alloc = [&](size_t bytes) {
    char* r = p; p += (bytes + 255) & ~(size_t)255; return (void*)r;
  };
  int*   flag      = (int*)  alloc(256);
  u16*   WqkvT     = (u16*)  alloc(3072ull * 1024 * 2);
  u16*   WoT       = (u16*)  alloc(1024ull * 1024 * 2);
  u16*   WinT      = (u16*)  alloc(4096ull * 1024 * 2);
  u16*   WoutT     = (u16*)  alloc(1024ull * 4096 * 2);
  float* biases    = (float*)alloc(9216 * 4);
  u16*   xn        = (u16*)  alloc(4096ull * 1024 * 2);  // reused as z
  u16*   q_hm      = (u16*)  alloc(16ull * 4096 * 64 * 2);
  u16*   k_hm      = (u16*)  alloc(16ull * 4096 * 64 * 2);
  u16*   vTws      = (u16*)  alloc(16ull * 64 * 4096 * 2);
  float* resid_mid = (float*)alloc(4096ull * 1024 * 4);
  u16*   h2        = (u16*)  alloc(4096ull * 1024 * 2);  // attn stats before ln2
  u16*   act       = (u16*)  alloc(4096ull * 4096 * 2);  // attn partials before MLP
  u16*   z = xn;
  u16*   Opart = act;              // 4096 slots x 4096 u16 = 32 MB (exact)
  float* stats = (float*)h2;       // 4096 slots x 128 fp32 = 2 MB < 8 MB

  detect_dtype<<<1, 256, 0, stream>>>((const unsigned int*)resid_pre, flag);

  pack_qkv_tiled<<<dim3(16, 48), 256, 0, stream>>>(flag, W_Q, W_K, W_V, WqkvT);
  transpose_tiled<<<dim3(16, 16), 256, 0, stream>>>(flag, W_O,   WoT,   1024, 1024);
  transpose_tiled<<<dim3(64, 16), 256, 0, stream>>>(flag, W_in,  WinT,  1024, 4096);
  transpose_tiled<<<dim3(16, 64), 256, 0, stream>>>(flag, W_out, WoutT, 4096, 1024);
  pack_biases<<<36, 256, 0, stream>>>(flag, b_Q, b_K, b_V, b_O, b_in, b_out, biases);

  ln_fwd<0><<<4096, 256, 0, stream>>>(flag, resid_pre, ln1_w, ln1_b, xn);
  // qkv -> head-major q/k + transposed v
  gemm_bt<4><<<dim3(3072 / 128, 4096 / 128), 256, 0, stream>>>(
      flag, xn, WqkvT, biases, nullptr, q_hm, k_hm, vTws, 4096, 3072, 1024);
  // split-K causal flash attention -> partials -> merge -> z
  attn_part<<<dim3(32, 32, 4), 256, 0, stream>>>(q_hm, k_hm, vTws, Opart, stats);
  attn_merge<<<dim3(32, 32), 256, 0, stream>>>(Opart, stats, z);
  // resid_mid = resid_pre + z @ W_O + b_O   (fp32)
  gemm_bt<2><<<dim3(1024 / 128, 4096 / 128), 256, 0, stream>>>(
      flag, z, WoT, biases + 3072, resid_pre, resid_mid, nullptr, nullptr, 4096, 1024, 1024);
  ln_fwd<1><<<4096, 256, 0, stream>>>(flag, resid_mid, ln2_w, ln2_b, h2);
  // act = relu(h2 @ W_in + b_in)
  gemm_bt<1><<<dim3(4096 / 128, 4096 / 128), 256, 0, stream>>>(
      flag, h2, WinT, biases + 4096, nullptr, act, nullptr, nullptr, 4096, 4096, 1024);
  // out = resid_mid + act @ W_out + b_out
  gemm_bt<3><<<dim3(1024 / 128, 4096 / 128), 256, 0, stream>>>(
      flag, act, WoutT, biases + 8192, resid_mid, d_out, nullptr, nullptr, 4096, 1024, 4096);
}

// Round 6
// 511.584 us; speedup vs baseline: 1.3198x; 1.0490x over previous
//
#include <hip/hip_runtime.h>
#include <stdint.h>

// ---------------------------------------------------------------------------
// TransformerBlock on MI355X (gfx950). Runtime dtype detection (fp32 vs bf16
// inputs), bf16-MFMA internal compute, fp32 accumulation + fp32 residual path.
// B=2 S=2048 D=1024 H=16 K=64 MLP=4096; tokens M = 4096.
// R6: GEMM re-tiled to 32x64 wave-tiles for occupancy (512-thr/128-tile for
// big GEMMs, 256-thr/64-tile for N=1024 GEMMs); attention q-tile 128 with
// shared K/V fragments across q-halves; coalesced Opart stores via LDS bounce.
// ---------------------------------------------------------------------------

typedef unsigned short u16;
typedef __bf16 bf16x8 __attribute__((ext_vector_type(8)));
typedef float  f32x4  __attribute__((ext_vector_type(4)));

#define QSCALE 0.18033688011112042f   // (1/sqrt(64)) * log2(e): softmax via exp2

__device__ __forceinline__ float bf2f(unsigned int u) {
  union { unsigned int u; float f; } v; v.u = u << 16; return v.f;
}
__device__ __forceinline__ u16 f2bf(float f) {
  union { float f; unsigned int u; } v; v.f = f;
  unsigned int r = v.u + 0x7FFFu + ((v.u >> 16) & 1u);   // RNE
  return (u16)(r >> 16);
}
__device__ __forceinline__ float loadf(const void* p, size_t i, int isf) {
  return isf ? ((const float*)p)[i] : bf2f(((const u16*)p)[i]);
}

typedef const __attribute__((address_space(1))) void* gas_t;
typedef __attribute__((address_space(3))) void* las_t;
__device__ __forceinline__ void gl_lds16(const u16* g, u16* l) {
  __builtin_amdgcn_global_load_lds((gas_t)g, (las_t)l, 16, 0, 0);
}

// ---------------------------------------------------------------------------
__global__ __launch_bounds__(256) void detect_dtype(
    const unsigned int* __restrict__ x, int* __restrict__ flag) {
  __shared__ int cnt;
  if (threadIdx.x == 0) cnt = 0;
  __syncthreads();
  int c = 0;
  for (int i = threadIdx.x; i < 512; i += 256) {
    unsigned int e = (x[i] >> 23) & 0xFFu;
    if (e >= 97u && e <= 157u) c++;
  }
  atomicAdd(&cnt, c);
  __syncthreads();
  if (threadIdx.x == 0) *flag = (cnt > 384) ? 1 : 0;
}

// ---------------------------------------------------------------------------
// Tiled transposes: 64x64 tiles through LDS (stride-65 pad -> 2-way = free).
// ---------------------------------------------------------------------------
__global__ __launch_bounds__(256) void pack_qkv_tiled(
    const int* __restrict__ flagp,
    const void* __restrict__ Wq, const void* __restrict__ Wk, const void* __restrict__ Wv,
    u16* __restrict__ WT) {
  __shared__ float t[64][65];
  const int isf = *flagp;
  const int tid = threadIdx.x;
  const int mh = blockIdx.y;            // mat*16 + h
  const int mat = mh >> 4, h = mh & 15;
  const int d0 = blockIdx.x << 6;       // d-tile
  const void* src = (mat == 0) ? Wq : (mat == 1) ? Wk : Wv;
  const float scale = (mat == 0) ? QSCALE : 1.f;
  const int lane = tid & 63, rr = tid >> 6;
  const size_t sbase = ((size_t)h << 16) + lane;
#pragma unroll
  for (int i = 0; i < 16; i++) {
    int d = i * 4 + rr;
    t[d][lane] = loadf(src, sbase + (size_t)(d0 + d) * 64, isf) * scale;
  }
  __syncthreads();
#pragma unroll
  for (int i = 0; i < 16; i++) {
    int k = i * 4 + rr;
    WT[((size_t)((mat << 10) + (h << 6) + k) << 10) + d0 + lane] = f2bf(t[lane][k]);
  }
}

__global__ __launch_bounds__(256) void transpose_tiled(
    const int* __restrict__ flagp, const void* __restrict__ src,
    u16* __restrict__ dst, int R, int C) {
  __shared__ float t[64][65];
  const int isf = *flagp;
  const int tid = threadIdx.x;
  const int c0 = blockIdx.x << 6, r0 = blockIdx.y << 6;
  const int lane = tid & 63, rr = tid >> 6;
#pragma unroll
  for (int i = 0; i < 16; i++) {
    int r = i * 4 + rr;
    t[r][lane] = loadf(src, (size_t)(r0 + r) * C + c0 + lane, isf);
  }
  __syncthreads();
#pragma unroll
  for (int i = 0; i < 16; i++) {
    int c = i * 4 + rr;
    dst[(size_t)(c0 + c) * R + r0 + lane] = f2bf(t[lane][c]);
  }
}

__global__ __launch_bounds__(256) void pack_biases(
    const int* __restrict__ flagp,
    const void* bq, const void* bk, const void* bv,
    const void* bO, const void* bin, const void* bout,
    float* __restrict__ out) {
  const int isf = *flagp;
  int i = blockIdx.x * 256 + threadIdx.x;
  float v;
  if (i < 1024)      v = loadf(bq,   i,        isf) * QSCALE;
  else if (i < 2048) v = loadf(bk,   i - 1024, isf);
  else if (i < 3072) v = loadf(bv,   i - 2048, isf);
  else if (i < 4096) v = loadf(bO,   i - 3072, isf);
  else if (i < 8192) v = loadf(bin,  i - 4096, isf);
  else               v = loadf(bout, i - 8192, isf);
  out[i] = v;
}

// ---------------------------------------------------------------------------
template<int SRC>
__global__ __launch_bounds__(256) void ln_fwd(
    const int* __restrict__ flagp, const void* __restrict__ xin,
    const void* __restrict__ w, const void* __restrict__ b,
    u16* __restrict__ out) {
  const int isf = *flagp;
  const int row = blockIdx.x, tid = threadIdx.x;
  const int col = tid << 2;
  const size_t base = ((size_t)row << 10) + col;
  float v[4];
#pragma unroll
  for (int i = 0; i < 4; i++)
    v[i] = (SRC == 1) ? ((const float*)xin)[base + i] : loadf(xin, base + i, isf);
  float s  = v[0] + v[1] + v[2] + v[3];
  float ss = v[0]*v[0] + v[1]*v[1] + v[2]*v[2] + v[3]*v[3];
#pragma unroll
  for (int mk = 32; mk >= 1; mk >>= 1) {
    s  += __shfl_xor(s,  mk, 64);
    ss += __shfl_xor(ss, mk, 64);
  }
  __shared__ float red[8];
  if ((tid & 63) == 0) { red[tid >> 6] = s; red[4 + (tid >> 6)] = ss; }
  __syncthreads();
  float S  = red[0] + red[1] + red[2] + red[3];
  float SS = red[4] + red[5] + red[6] + red[7];
  float mean = S * (1.f / 1024.f);
  float var  = SS * (1.f / 1024.f) - mean * mean;
  float rstd = rsqrtf(var + 1e-5f);
  u16 e[4];
#pragma unroll
  for (int i = 0; i < 4; i++) {
    float wv = loadf(w, col + i, isf);
    float bv = loadf(b, col + i, isf);
    e[i] = f2bf((v[i] - mean) * rstd * wv + bv);
  }
  uint2 o;
  o.x = (unsigned)e[0] | ((unsigned)e[1] << 16);
  o.y = (unsigned)e[2] | ((unsigned)e[3] << 16);
  *(uint2*)(out + base) = o;
}

// ---------------------------------------------------------------------------
// GEMM C[M,N] = A[M,K] @ BT[N,K]^T + bias. Tile TM x 128, TM*4 threads,
// wave-tile 32x64 (acc 2x4 -> 32 AGPR) for occupancy.
// MODE 1: relu+bf16; 2: +flagged resid -> fp32 out; 3: +fp32 resid -> flagged
// MODE 4: QKV epilogue -> q_hm[h][t][64] (out), k_hm (out2), vT[h][f][4096] (out3)
// ---------------------------------------------------------------------------
template<int MODE, int TM>
__global__ __launch_bounds__(TM * 4) void gemm_bt(
    const int* __restrict__ flagp,
    const u16* __restrict__ A, const u16* __restrict__ BT,
    const float* __restrict__ bias, const void* __restrict__ resid,
    void* __restrict__ out, void* __restrict__ out2, void* __restrict__ out3,
    int M, int N, int K) {
  __shared__ u16 as[TM * 32];
  __shared__ u16 bs[128 * 32];
  int isf = 0;
  if (MODE == 2 || MODE == 3) isf = *flagp;
  const int tid = threadIdx.x;
  const int L = tid & 63, w = tid >> 6;
  const int wm = (w >> 1) << 5, wn = (w & 1) << 6;
  const int row0 = blockIdx.y * TM, col0 = blockIdx.x << 7;
  const int m = L & 15, quad = L >> 4;

  f32x4 zero4 = {0.f, 0.f, 0.f, 0.f};
  f32x4 acc[2][4];
#pragma unroll
  for (int i = 0; i < 2; i++)
#pragma unroll
    for (int j = 0; j < 4; j++) acc[i][j] = zero4;

  const int tm = tid >> 2;
  const int tk = (tid & 3) << 3;
  const u16* Ag  = A  + (size_t)(row0 + tm) * K + tk;
  const u16* Bg  = BT + (size_t)(col0 + tm) * K + tk;
  const u16* Bg2 = Bg + (size_t)64 * K;          // TM==64 only
  u16* asl  = &as[tid * 8];
  u16* bsl  = &bs[tid * 8];
  u16* bsl2 = &bs[2048 + tid * 8];               // TM==64 only

  const int aoff = (wm + m) * 32 + quad * 8;
  const int boff = (wn + m) * 32 + quad * 8;

  for (int kk = 0; kk < K; kk += 32) {
    __syncthreads();
    gl_lds16(Ag + kk, asl);
    gl_lds16(Bg + kk, bsl);
    if (TM == 64) gl_lds16(Bg2 + kk, bsl2);
    __syncthreads();
    bf16x8 af[2], bfr[4];
#pragma unroll
    for (int i = 0; i < 2; i++) af[i]  = *(const bf16x8*)&as[aoff + i * 512];
#pragma unroll
    for (int j = 0; j < 4; j++) bfr[j] = *(const bf16x8*)&bs[boff + j * 512];
#pragma unroll
    for (int i = 0; i < 2; i++)
#pragma unroll
      for (int j = 0; j < 4; j++)
        acc[i][j] = __builtin_amdgcn_mfma_f32_16x16x32_bf16(af[i], bfr[j], acc[i][j], 0, 0, 0);
  }

#pragma unroll
  for (int j = 0; j < 4; j++) {
    const int col = col0 + wn + j * 16 + m;
    const float bval = bias[col];
    if (MODE == 4) {
      const int sel = col >> 10;
      const int hh  = (col >> 6) & 15;
      const int f   = col & 63;
#pragma unroll
      for (int i = 0; i < 2; i++) {
        const int rowb = row0 + wm + i * 16 + quad * 4;
        if (sel < 2) {
          u16* dst = (u16*)(sel ? out2 : out);
#pragma unroll
          for (int r = 0; r < 4; r++)
            dst[((((size_t)hh << 12) + rowb + r) << 6) + f] = f2bf(acc[i][j][r] + bval);
        } else {
          u16 e[4];
#pragma unroll
          for (int r = 0; r < 4; r++) e[r] = f2bf(acc[i][j][r] + bval);
          uint2 o;
          o.x = (unsigned)e[0] | ((unsigned)e[1] << 16);
          o.y = (unsigned)e[2] | ((unsigned)e[3] << 16);
          *(uint2*)&((u16*)out3)[(((size_t)hh * 64 + f) << 12) + rowb] = o;
        }
      }
    } else {
#pragma unroll
      for (int i = 0; i < 2; i++) {
        const int rowb = row0 + wm + i * 16 + quad * 4;
#pragma unroll
        for (int r = 0; r < 4; r++) {
          float vv = acc[i][j][r] + bval;
          size_t idx = (size_t)(rowb + r) * N + col;
          if (MODE == 1) {
            ((u16*)out)[idx] = f2bf(fmaxf(vv, 0.f));
          } else if (MODE == 2) {
            ((float*)out)[idx] = vv + loadf(resid, idx, isf);
          } else if (MODE == 3) {
            float o = vv + ((const float*)resid)[idx];
            if (isf) ((float*)out)[idx] = o;
            else     ((u16*)out)[idx]   = f2bf(o);
          }
        }
      }
    }
  }
}

// ---------------------------------------------------------------------------
// Flash attention, split-K. Block = (combo=h*2+b, qt128, ci): 128 q-rows
// (4 waves x 32, two 16-row halves/wave) vs k-chunk of <=512 (<=4 steps of
// 128). K-tile LDS frags shared across halves; V B-frags shared via fb-outer.
// Outputs: unnormalized O (coalesced via LDS bounce) + (m,l) stats.
// ---------------------------------------------------------------------------
__global__ __launch_bounds__(256) void attn_part(
    const u16* __restrict__ qh, const u16* __restrict__ kh,
    const u16* __restrict__ vT, u16* __restrict__ Opart,
    float* __restrict__ stats) {
  const int combo = blockIdx.x;      // h*2 + b
  const int qt = blockIdx.y;         // 0..15 (128-row q-tiles)
  const int ci = blockIdx.z;         // 0..3
  const int q0 = qt << 7;
  const int nc = (q0 + 128 + 511) >> 9;
  if (ci >= nc) return;
  const int k_lo = ci << 9;
  const int k_hi = min(k_lo + 512, q0 + 128);
  const int nsteps = (k_hi - k_lo + 127) >> 7;

  __shared__ u16 kS[128 * 72];       // K tile [tok][64+8 pad]
  __shared__ u16 vS[64 * 136];       // V^T tile [f][128+8 pad]
  __shared__ u16 pS[4 * 32 * 136];   // per-wave P [32 q][128+8 pad]
  const int tid = threadIdx.x, L = tid & 63, w = tid >> 6;
  const int m = L & 15, quad = L >> 4;
  const int h = combo >> 1, b = combo & 1;
  const size_t tb = (size_t)b * 2048;
  const size_t hbase = (size_t)h * 4096;
  u16* pw = &pS[w * (32 * 136)];

  bf16x8 aq[2][2];
#pragma unroll
  for (int hf = 0; hf < 2; hf++) {
    const u16* qp = qh + ((hbase + tb + q0 + w * 32 + hf * 16 + m) << 6) + quad * 8;
    aq[hf][0] = *(const bf16x8*)qp;
    aq[hf][1] = *(const bf16x8*)(qp + 32);
  }

  f32x4 zero4 = {0.f, 0.f, 0.f, 0.f};
  f32x4 O[2][4];
  float mrow[2][4], lrow[2][4];
#pragma unroll
  for (int hf = 0; hf < 2; hf++)
#pragma unroll
    for (int r = 0; r < 4; r++) {
      O[hf][r] = zero4; mrow[hf][r] = -30000.f; lrow[hf][r] = 0.f;
    }

  const int krow[4] = { (0*256+tid) >> 3, (1*256+tid) >> 3, (2*256+tid) >> 3, (3*256+tid) >> 3 };
  const int kc = tid & 7;
  const int vf[4] = { (0*256+tid) >> 4, (1*256+tid) >> 4, (2*256+tid) >> 4, (3*256+tid) >> 4 };
  const int vc = tid & 15;

  int4 kr[4], vr[4];
#pragma unroll
  for (int i = 0; i < 4; i++) {
    kr[i] = *(const int4*)(kh + ((hbase + tb + k_lo + krow[i]) << 6) + kc * 8);
    vr[i] = *(const int4*)(vT + (((size_t)h * 64 + vf[i]) << 12) + tb + k_lo + vc * 8);
  }

  for (int j = 0; j < nsteps; j++) {
    const int k0 = k_lo + (j << 7);
    __syncthreads();
#pragma unroll
    for (int i = 0; i < 4; i++) {
      *(int4*)&kS[krow[i] * 72 + kc * 8] = kr[i];
      *(int4*)&vS[vf[i] * 136 + vc * 8] = vr[i];
    }
    __syncthreads();
    if (j + 1 < nsteps) {
      const int k1 = k_lo + ((j + 1) << 7);
#pragma unroll
      for (int i = 0; i < 4; i++) {
        kr[i] = *(const int4*)(kh + ((hbase + tb + k1 + krow[i]) << 6) + kc * 8);
        vr[i] = *(const int4*)(vT + (((size_t)h * 64 + vf[i]) << 12) + tb + k1 + vc * 8);
      }
    }
    // S = Q K^T, both q-halves sharing the K-frag reads
    f32x4 sc[2][8];
#pragma unroll
    for (int cb = 0; cb < 8; cb++) {
      const int kb = (cb * 16 + m) * 72;
      bf16x8 k0f = *(const bf16x8*)&kS[kb + quad * 8];
      bf16x8 k1f = *(const bf16x8*)&kS[kb + 32 + quad * 8];
#pragma unroll
      for (int hf = 0; hf < 2; hf++) {
        f32x4 t = zero4;
        t = __builtin_amdgcn_mfma_f32_16x16x32_bf16(aq[hf][0], k0f, t, 0, 0, 0);
        t = __builtin_amdgcn_mfma_f32_16x16x32_bf16(aq[hf][1], k1f, t, 0, 0, 0);
        sc[hf][cb] = t;
      }
    }
    if (k0 + 128 > q0) {   // touches diagonal: causal mask
#pragma unroll
      for (int hf = 0; hf < 2; hf++)
#pragma unroll
        for (int cb = 0; cb < 8; cb++)
#pragma unroll
          for (int r = 0; r < 4; r++) {
            int rowg = q0 + w * 32 + hf * 16 + quad * 4 + r;
            int colg = k0 + cb * 16 + m;
            if (colg > rowg) sc[hf][cb][r] = -30000.f;
          }
    }
    // online softmax per half (row groups = 16 lanes)
#pragma unroll
    for (int hf = 0; hf < 2; hf++)
#pragma unroll
      for (int r = 0; r < 4; r++) {
        float mx = sc[hf][0][r];
#pragma unroll
        for (int cb = 1; cb < 8; cb++) mx = fmaxf(mx, sc[hf][cb][r]);
        mx = fmaxf(mx, __shfl_xor(mx, 1, 64));
        mx = fmaxf(mx, __shfl_xor(mx, 2, 64));
        mx = fmaxf(mx, __shfl_xor(mx, 4, 64));
        mx = fmaxf(mx, __shfl_xor(mx, 8, 64));
        float mnew = fmaxf(mrow[hf][r], mx);
        float alpha = __builtin_amdgcn_exp2f(mrow[hf][r] - mnew);
        float sum = 0.f;
#pragma unroll
        for (int cb = 0; cb < 8; cb++) {
          float pv = __builtin_amdgcn_exp2f(sc[hf][cb][r] - mnew);
          sc[hf][cb][r] = pv; sum += pv;
        }
        sum += __shfl_xor(sum, 1, 64);
        sum += __shfl_xor(sum, 2, 64);
        sum += __shfl_xor(sum, 4, 64);
        sum += __shfl_xor(sum, 8, 64);
        lrow[hf][r] = lrow[hf][r] * alpha + sum;
        mrow[hf][r] = mnew;
#pragma unroll
        for (int fb = 0; fb < 4; fb++) O[hf][fb][r] *= alpha;
      }
    // P: C-layout -> per-wave LDS (rows = 32 q) -> A-layout
#pragma unroll
    for (int hf = 0; hf < 2; hf++)
#pragma unroll
      for (int cb = 0; cb < 8; cb++)
#pragma unroll
        for (int r = 0; r < 4; r++)
          pw[(hf * 16 + quad * 4 + r) * 136 + cb * 16 + m] = f2bf(sc[hf][cb][r]);
    bf16x8 ap[2][4];
#pragma unroll
    for (int hf = 0; hf < 2; hf++)
#pragma unroll
      for (int kkc = 0; kkc < 4; kkc++)
        ap[hf][kkc] = *(const bf16x8*)&pw[(hf * 16 + m) * 136 + kkc * 32 + quad * 8];
#pragma unroll
    for (int fb = 0; fb < 4; fb++) {
      bf16x8 bv[4];
#pragma unroll
      for (int kkc = 0; kkc < 4; kkc++)
        bv[kkc] = *(const bf16x8*)&vS[(fb * 16 + m) * 136 + kkc * 32 + quad * 8];
#pragma unroll
      for (int hf = 0; hf < 2; hf++)
#pragma unroll
        for (int kkc = 0; kkc < 4; kkc++)
          O[hf][fb] = __builtin_amdgcn_mfma_f32_16x16x32_bf16(ap[hf][kkc], bv[kkc], O[hf][fb], 0, 0, 0);
    }
  }

  // O -> LDS bounce -> coalesced 1KB global stores
#pragma unroll
  for (int hf = 0; hf < 2; hf++)
#pragma unroll
    for (int fb = 0; fb < 4; fb++)
#pragma unroll
      for (int r = 0; r < 4; r++)
        pw[(hf * 16 + quad * 4 + r) * 136 + fb * 16 + m] = f2bf(O[hf][fb][r]);
  const int slot = (combo * 16 + qt) * 4 + ci;
  u16* op = Opart + (size_t)slot * 8192;
#pragma unroll
  for (int i = 0; i < 4; i++) {
    int rl = (L >> 3) + i * 8;       // 0..31
    int c = L & 7;
    int4 vv = *(const int4*)&pw[rl * 136 + c * 8];
    *(int4*)&op[(w * 32 + rl) * 64 + c * 8] = vv;
  }
  if (m == 0) {
#pragma unroll
    for (int hf = 0; hf < 2; hf++)
#pragma unroll
      for (int r = 0; r < 4; r++) {
        int q = w * 32 + hf * 16 + quad * 4 + r;
        stats[slot * 256 + q]       = mrow[hf][r];
        stats[slot * 256 + 128 + q] = lrow[hf][r];
      }
  }
}

// merge partials -> z [t][1024]
__global__ __launch_bounds__(256) void attn_merge(
    const u16* __restrict__ Opart, const float* __restrict__ stats,
    u16* __restrict__ z) {
  const int combo = blockIdx.x, qt = blockIdx.y;
  const int h = combo >> 1, b = combo & 1;
  const int q0 = qt << 7;
  const int nc = (q0 + 128 + 511) >> 9;
  const int tid = threadIdx.x;
  const int t = tid >> 1;            // row 0..127
  const int f0 = (tid & 1) << 5;     // 0 / 32
  const int slot0 = (combo * 16 + qt) * 4;
  float M = -3e4f;
  for (int ci = 0; ci < nc; ci++)
    M = fmaxf(M, stats[(slot0 + ci) * 256 + t]);
  float acc[32];
#pragma unroll
  for (int e = 0; e < 32; e++) acc[e] = 0.f;
  float ltot = 0.f;
  for (int ci = 0; ci < nc; ci++) {
    float mi = stats[(slot0 + ci) * 256 + t];
    float li = stats[(slot0 + ci) * 256 + 128 + t];
    float wgt = exp2f(mi - M);
    ltot += wgt * li;
    const u16* op = Opart + (size_t)(slot0 + ci) * 8192 + t * 64 + f0;
#pragma unroll
    for (int c = 0; c < 4; c++) {
      union { int4 v; u16 u[8]; } a;
      a.v = *(const int4*)(op + c * 8);
#pragma unroll
      for (int e = 0; e < 8; e++) acc[c * 8 + e] += wgt * bf2f(a.u[e]);
    }
  }
  float inv = 1.f / ltot;
  size_t tok = (size_t)b * 2048 + q0 + t;
  u16* zp = &z[tok * 1024 + h * 64 + f0];
#pragma unroll
  for (int c = 0; c < 4; c++) {
    union { int4 v; u16 u[8]; } o;
#pragma unroll
    for (int e = 0; e < 8; e++) o.u[e] = f2bf(acc[c * 8 + e] * inv);
    *(int4*)(zp + c * 8) = o.v;
  }
}

// ---------------------------------------------------------------------------
extern "C" void kernel_launch(void* const* d_in, const int* in_sizes, int n_in,
                              void* d_out, int out_size, void* d_ws, size_t ws_size,
                              hipStream_t stream) {
  (void)in_sizes; (void)n_in; (void)out_size; (void)ws_size;
  const void* resid_pre = d_in[0];
  const void* ln1_w = d_in[1];
  const void* ln1_b = d_in[2];
  const void* W_Q   = d_in[3];
  const void* b_Q   = d_in[4];
  const void* W_K   = d_in[5];
  const void* b_K   = d_in[6];
  const void* W_V   = d_in[7];
  const void* b_V   = d_in[8];
  const void* W_O   = d_in[9];
  const void* b_O   = d_in[10];
  const void* ln2_w = d_in[11];
  const void* ln2_b = d_in[12];
  const void* W_in  = d_in[13];
  const void* b_in  = d_in[14];
  const void* W_out = d_in[15];
  const void* b_out = d_in[16];

  char* p = (char*)d_ws;
  auto alloc = [&](size_t bytes) {
    char* r = p; p += (bytes + 255) & ~(size_t)255; return (void*)r;
  };
  int*   flag      = (int*)  alloc(256);
  u16*   WqkvT     = (u16*)  alloc(3072ull * 1024 * 2);
  u16*   WoT       = (u16*)  alloc(1024ull * 1024 * 2);
  u16*   WinT      = (u16*)  alloc(4096ull * 1024 * 2);
  u16*   WoutT     = (u16*)  alloc(1024ull * 4096 * 2);
  float* biases    = (float*)alloc(9216 * 4);
  u16*   xn        = (u16*)  alloc(4096ull * 1024 * 2);  // reused as z
  u16*   q_hm      = (u16*)  alloc(16ull * 4096 * 64 * 2);
  u16*   k_hm      = (u16*)  alloc(16ull * 4096 * 64 * 2);
  u16*   vTws      = (u16*)  alloc(16ull * 64 * 4096 * 2);
  float* resid_mid = (float*)alloc(4096ull * 1024 * 4);
  u16*   h2        = (u16*)  alloc(4096ull * 1024 * 2);  // attn stats before ln2
  u16*   act       = (u16*)  alloc(4096ull * 4096 * 2);  // attn partials before MLP
  u16*   z = xn;
  u16*   Opart = act;              // 2048 slots x 8192 u16 = 32 MB (exact)
  float* stats = (float*)h2;       // 2048 slots x 256 fp32 = 2 MB < 8 MB

  detect_dtype<<<1, 256, 0, stream>>>((const unsigned int*)resid_pre, flag);

  pack_qkv_tiled<<<dim3(16, 48), 256, 0, stream>>>(flag, W_Q, W_K, W_V, WqkvT);
  transpose_tiled<<<dim3(16, 16), 256, 0, stream>>>(flag, W_O,   WoT,   1024, 1024);
  transpose_tiled<<<dim3(64, 16), 256, 0, stream>>>(flag, W_in,  WinT,  1024, 4096);
  transpose_tiled<<<dim3(16, 64), 256, 0, stream>>>(flag, W_out, WoutT, 4096, 1024);
  pack_biases<<<36, 256, 0, stream>>>(flag, b_Q, b_K, b_V, b_O, b_in, b_out, biases);

  ln_fwd<0><<<4096, 256, 0, stream>>>(flag, resid_pre, ln1_w, ln1_b, xn);
  // qkv -> head-major q/k + transposed v
  gemm_bt<4, 128><<<dim3(24, 32), 512, 0, stream>>>(
      flag, xn, WqkvT, biases, nullptr, q_hm, k_hm, vTws, 4096, 3072, 1024);
  // split-K causal flash attention -> partials -> merge -> z
  attn_part<<<dim3(32, 16, 4), 256, 0, stream>>>(q_hm, k_hm, vTws, Opart, stats);
  attn_merge<<<dim3(32, 16), 256, 0, stream>>>(Opart, stats, z);
  // resid_mid = resid_pre + z @ W_O + b_O   (fp32)
  gemm_bt<2, 64><<<dim3(8, 64), 256, 0, stream>>>(
      flag, z, WoT, biases + 3072, resid_pre, resid_mid, nullptr, nullptr, 4096, 1024, 1024);
  ln_fwd<1><<<4096, 256, 0, stream>>>(flag, resid_mid, ln2_w, ln2_b, h2);
  // act = relu(h2 @ W_in + b_in)
  gemm_bt<1, 128><<<dim3(32, 32), 512, 0, stream>>>(
      flag, h2, WinT, biases + 4096, nullptr, act, nullptr, nullptr, 4096, 4096, 1024);
  // out = resid_mid + act @ W_out + b_out
  gemm_bt<3, 64><<<dim3(8, 64), 256, 0, stream>>>(
      flag, act, WoutT, biases + 8192, resid_mid, d_out, nullptr, nullptr, 4096, 1024, 4096);
}

// Round 7
// 498.550 us; speedup vs baseline: 1.3543x; 1.0261x over previous
//
#include <hip/hip_runtime.h>
#include <stdint.h>

// ---------------------------------------------------------------------------
// TransformerBlock on MI355X (gfx950). Runtime dtype detection (fp32 vs bf16
// inputs), bf16-MFMA internal compute, fp32 accumulation + fp32 residual path.
// B=2 S=2048 D=1024 H=16 K=64 MLP=4096; tokens M = 4096.
// R7: attention rewritten around the S^T trick: 16x16x16 MFMA C/D layout ==
// B-operand layout, so P^T chains K·Q^T -> V^T·P^T with zero LDS round-trip
// and 2 shuffles/step (was 64); row-sum via ones-MFMA. GEMMs back to the
// m97-proven 64x64 wave tile + XCD-swizzled 1-D grid for L2 locality.
// ---------------------------------------------------------------------------

typedef unsigned short u16;
typedef __bf16 bf16x8 __attribute__((ext_vector_type(8)));
typedef __bf16 bf16x4 __attribute__((ext_vector_type(4)));
typedef short  s16x4  __attribute__((ext_vector_type(4)));
typedef float  f32x4  __attribute__((ext_vector_type(4)));

#define QSCALE 0.18033688011112042f   // (1/sqrt(64)) * log2(e): softmax via exp2

__device__ __forceinline__ float bf2f(unsigned int u) {
  union { unsigned int u; float f; } v; v.u = u << 16; return v.f;
}
__device__ __forceinline__ u16 f2bf(float f) {
  union { float f; unsigned int u; } v; v.f = f;
  unsigned int r = v.u + 0x7FFFu + ((v.u >> 16) & 1u);   // RNE
  return (u16)(r >> 16);
}
__device__ __forceinline__ float loadf(const void* p, size_t i, int isf) {
  return isf ? ((const float*)p)[i] : bf2f(((const u16*)p)[i]);
}

typedef const __attribute__((address_space(1))) void* gas_t;
typedef __attribute__((address_space(3))) void* las_t;
__device__ __forceinline__ void gl_lds16(const u16* g, u16* l) {
  __builtin_amdgcn_global_load_lds((gas_t)g, (las_t)l, 16, 0, 0);
}

// 16x16x16 bf16 MFMA wrapper (builtin name differs across ROCm revisions)
__device__ __forceinline__ f32x4 mfma16(s16x4 a, s16x4 b, f32x4 c) {
#if __has_builtin(__builtin_amdgcn_mfma_f32_16x16x16_bf16)
  return __builtin_amdgcn_mfma_f32_16x16x16_bf16(
      __builtin_bit_cast(bf16x4, a), __builtin_bit_cast(bf16x4, b), c, 0, 0, 0);
#else
  return __builtin_amdgcn_mfma_f32_16x16x16bf16_1k(a, b, c, 0, 0, 0);
#endif
}

// ---------------------------------------------------------------------------
__global__ __launch_bounds__(256) void detect_dtype(
    const unsigned int* __restrict__ x, int* __restrict__ flag) {
  __shared__ int cnt;
  if (threadIdx.x == 0) cnt = 0;
  __syncthreads();
  int c = 0;
  for (int i = threadIdx.x; i < 512; i += 256) {
    unsigned int e = (x[i] >> 23) & 0xFFu;
    if (e >= 97u && e <= 157u) c++;
  }
  atomicAdd(&cnt, c);
  __syncthreads();
  if (threadIdx.x == 0) *flag = (cnt > 384) ? 1 : 0;
}

// ---------------------------------------------------------------------------
// Tiled transposes: 64x64 tiles through LDS (stride-65 pad -> 2-way = free).
// ---------------------------------------------------------------------------
__global__ __launch_bounds__(256) void pack_qkv_tiled(
    const int* __restrict__ flagp,
    const void* __restrict__ Wq, const void* __restrict__ Wk, const void* __restrict__ Wv,
    u16* __restrict__ WT) {
  __shared__ float t[64][65];
  const int isf = *flagp;
  const int tid = threadIdx.x;
  const int mh = blockIdx.y;            // mat*16 + h
  const int mat = mh >> 4, h = mh & 15;
  const int d0 = blockIdx.x << 6;       // d-tile
  const void* src = (mat == 0) ? Wq : (mat == 1) ? Wk : Wv;
  const float scale = (mat == 0) ? QSCALE : 1.f;
  const int lane = tid & 63, rr = tid >> 6;
  const size_t sbase = ((size_t)h << 16) + lane;
#pragma unroll
  for (int i = 0; i < 16; i++) {
    int d = i * 4 + rr;
    t[d][lane] = loadf(src, sbase + (size_t)(d0 + d) * 64, isf) * scale;
  }
  __syncthreads();
#pragma unroll
  for (int i = 0; i < 16; i++) {
    int k = i * 4 + rr;
    WT[((size_t)((mat << 10) + (h << 6) + k) << 10) + d0 + lane] = f2bf(t[lane][k]);
  }
}

__global__ __launch_bounds__(256) void transpose_tiled(
    const int* __restrict__ flagp, const void* __restrict__ src,
    u16* __restrict__ dst, int R, int C) {
  __shared__ float t[64][65];
  const int isf = *flagp;
  const int tid = threadIdx.x;
  const int c0 = blockIdx.x << 6, r0 = blockIdx.y << 6;
  const int lane = tid & 63, rr = tid >> 6;
#pragma unroll
  for (int i = 0; i < 16; i++) {
    int r = i * 4 + rr;
    t[r][lane] = loadf(src, (size_t)(r0 + r) * C + c0 + lane, isf);
  }
  __syncthreads();
#pragma unroll
  for (int i = 0; i < 16; i++) {
    int c = i * 4 + rr;
    dst[(size_t)(c0 + c) * R + r0 + lane] = f2bf(t[lane][c]);
  }
}

__global__ __launch_bounds__(256) void pack_biases(
    const int* __restrict__ flagp,
    const void* bq, const void* bk, const void* bv,
    const void* bO, const void* bin, const void* bout,
    float* __restrict__ out) {
  const int isf = *flagp;
  int i = blockIdx.x * 256 + threadIdx.x;
  float v;
  if (i < 1024)      v = loadf(bq,   i,        isf) * QSCALE;
  else if (i < 2048) v = loadf(bk,   i - 1024, isf);
  else if (i < 3072) v = loadf(bv,   i - 2048, isf);
  else if (i < 4096) v = loadf(bO,   i - 3072, isf);
  else if (i < 8192) v = loadf(bin,  i - 4096, isf);
  else               v = loadf(bout, i - 8192, isf);
  out[i] = v;
}

// ---------------------------------------------------------------------------
template<int SRC>
__global__ __launch_bounds__(256) void ln_fwd(
    const int* __restrict__ flagp, const void* __restrict__ xin,
    const void* __restrict__ w, const void* __restrict__ b,
    u16* __restrict__ out) {
  const int isf = *flagp;
  const int row = blockIdx.x, tid = threadIdx.x;
  const int col = tid << 2;
  const size_t base = ((size_t)row << 10) + col;
  float v[4];
#pragma unroll
  for (int i = 0; i < 4; i++)
    v[i] = (SRC == 1) ? ((const float*)xin)[base + i] : loadf(xin, base + i, isf);
  float s  = v[0] + v[1] + v[2] + v[3];
  float ss = v[0]*v[0] + v[1]*v[1] + v[2]*v[2] + v[3]*v[3];
#pragma unroll
  for (int mk = 32; mk >= 1; mk >>= 1) {
    s  += __shfl_xor(s,  mk, 64);
    ss += __shfl_xor(ss, mk, 64);
  }
  __shared__ float red[8];
  if ((tid & 63) == 0) { red[tid >> 6] = s; red[4 + (tid >> 6)] = ss; }
  __syncthreads();
  float S  = red[0] + red[1] + red[2] + red[3];
  float SS = red[4] + red[5] + red[6] + red[7];
  float mean = S * (1.f / 1024.f);
  float var  = SS * (1.f / 1024.f) - mean * mean;
  float rstd = rsqrtf(var + 1e-5f);
  u16 e[4];
#pragma unroll
  for (int i = 0; i < 4; i++) {
    float wv = loadf(w, col + i, isf);
    float bv = loadf(b, col + i, isf);
    e[i] = f2bf((v[i] - mean) * rstd * wv + bv);
  }
  uint2 o;
  o.x = (unsigned)e[0] | ((unsigned)e[1] << 16);
  o.y = (unsigned)e[2] | ((unsigned)e[3] << 16);
  *(uint2*)(out + base) = o;
}

// ---------------------------------------------------------------------------
// GEMM C[M,N] = A[M,K] @ BT[N,K]^T + bias. m97 structure, 256 thr / 4 waves.
// TM=128: wave tile 64x64 (acc 4x4). TM=64: wave tile 32x64 (acc 2x4).
// 1-D grid with XCD swizzle: xcd=L&7 owns row stripe of SH tiles; column
// index advances in lockstep across XCDs (B tile fetched ~once chip-wide).
// MODE 1: relu+bf16; 2: +flagged resid -> fp32; 3: +fp32 resid -> flagged out
// MODE 4: QKV epilogue -> q_hm[h][t][64], k_hm, vT[h][f][4096]
// ---------------------------------------------------------------------------
template<int MODE, int TM>
__global__ __launch_bounds__(256) void gemm_bt(
    const int* __restrict__ flagp,
    const u16* __restrict__ A, const u16* __restrict__ BT,
    const float* __restrict__ bias, const void* __restrict__ resid,
    void* __restrict__ out, void* __restrict__ out2, void* __restrict__ out3,
    int M, int N, int K, int SHL) {
  constexpr int WR = TM / 32;          // row-frags per wave
  __shared__ u16 as[TM * 32];
  __shared__ u16 bs[128 * 32];
  int isf = 0;
  if (MODE == 2 || MODE == 3) isf = *flagp;
  const int Lb = blockIdx.x;
  const int xcd = Lb & 7, sidx = Lb >> 3;
  const int SH = 1 << SHL;
  const int by = xcd * SH + (sidx & (SH - 1));
  const int bx = sidx >> SHL;
  const int tid = threadIdx.x;
  const int L = tid & 63, w = tid >> 6;
  const int wm = (w >> 1) * (TM >> 1), wn = (w & 1) << 6;
  const int row0 = by * TM, col0 = bx << 7;
  const int m = L & 15, quad = L >> 4;

  f32x4 zero4 = {0.f, 0.f, 0.f, 0.f};
  f32x4 acc[WR][4];
#pragma unroll
  for (int i = 0; i < WR; i++)
#pragma unroll
    for (int j = 0; j < 4; j++) acc[i][j] = zero4;

  const int tm = tid >> 2;
  const int tk = (tid & 3) << 3;
  const u16* Ag  = A  + (size_t)(row0 + tm) * K + tk;
  const u16* Ag2 = Ag + (size_t)64 * K;          // TM==128 only
  const u16* Bg  = BT + (size_t)(col0 + tm) * K + tk;
  const u16* Bg2 = Bg + (size_t)64 * K;
  u16* asl  = &as[tid * 8];
  u16* asl2 = &as[2048 + tid * 8];
  u16* bsl  = &bs[tid * 8];
  u16* bsl2 = &bs[2048 + tid * 8];

  const int aoff = (wm + m) * 32 + quad * 8;
  const int boff = (wn + m) * 32 + quad * 8;

  for (int kk = 0; kk < K; kk += 32) {
    __syncthreads();
    gl_lds16(Ag + kk, asl);
    if (TM == 128) gl_lds16(Ag2 + kk, asl2);
    gl_lds16(Bg + kk, bsl);
    gl_lds16(Bg2 + kk, bsl2);
    __syncthreads();
    bf16x8 af[WR], bfr[4];
#pragma unroll
    for (int i = 0; i < WR; i++) af[i]  = *(const bf16x8*)&as[aoff + i * 512];
#pragma unroll
    for (int j = 0; j < 4; j++) bfr[j] = *(const bf16x8*)&bs[boff + j * 512];
#pragma unroll
    for (int i = 0; i < WR; i++)
#pragma unroll
      for (int j = 0; j < 4; j++)
        acc[i][j] = __builtin_amdgcn_mfma_f32_16x16x32_bf16(af[i], bfr[j], acc[i][j], 0, 0, 0);
  }

#pragma unroll
  for (int j = 0; j < 4; j++) {
    const int col = col0 + wn + j * 16 + m;
    const float bval = bias[col];
    if (MODE == 4) {
      const int sel = col >> 10;
      const int hh  = (col >> 6) & 15;
      const int f   = col & 63;
#pragma unroll
      for (int i = 0; i < WR; i++) {
        const int rowb = row0 + wm + i * 16 + quad * 4;
        if (sel < 2) {
          u16* dst = (u16*)(sel ? out2 : out);
#pragma unroll
          for (int r = 0; r < 4; r++)
            dst[((((size_t)hh << 12) + rowb + r) << 6) + f] = f2bf(acc[i][j][r] + bval);
        } else {
          u16 e[4];
#pragma unroll
          for (int r = 0; r < 4; r++) e[r] = f2bf(acc[i][j][r] + bval);
          uint2 o;
          o.x = (unsigned)e[0] | ((unsigned)e[1] << 16);
          o.y = (unsigned)e[2] | ((unsigned)e[3] << 16);
          *(uint2*)&((u16*)out3)[(((size_t)hh * 64 + f) << 12) + rowb] = o;
        }
      }
    } else {
#pragma unroll
      for (int i = 0; i < WR; i++) {
        const int rowb = row0 + wm + i * 16 + quad * 4;
#pragma unroll
        for (int r = 0; r < 4; r++) {
          float vv = acc[i][j][r] + bval;
          size_t idx = (size_t)(rowb + r) * N + col;
          if (MODE == 1) {
            ((u16*)out)[idx] = f2bf(fmaxf(vv, 0.f));
          } else if (MODE == 2) {
            ((float*)out)[idx] = vv + loadf(resid, idx, isf);
          } else if (MODE == 3) {
            float o = vv + ((const float*)resid)[idx];
            if (isf) ((float*)out)[idx] = o;
            else     ((u16*)out)[idx]   = f2bf(o);
          }
        }
      }
    }
  }
}

// ---------------------------------------------------------------------------
// Flash attention, split-K, transposed-MFMA form. Block = (combo, qt64, ci):
// 64 q (4 waves x 16, q = lane&15 column) vs k-chunk <=512 (<=4 steps of 128).
// Per 16k-tile: S^T = K·Q^T (16x16x16); its C/D regs ARE the B-operand for
// O^T = V^T·P^T. l via ones-MFMA. Per-lane scalar softmax state; 2 shuffles
// per step. Outputs unnormalized O (coalesced via LDS bounce) + (m,l) stats.
// ---------------------------------------------------------------------------
__global__ __launch_bounds__(256, 3) void attn_part(
    const u16* __restrict__ qh, const u16* __restrict__ kh,
    const u16* __restrict__ vT, u16* __restrict__ Opart,
    float* __restrict__ stats) {
  const int combo = blockIdx.x;      // h*2 + b
  const int qt = blockIdx.y;         // 0..31 (64-row q-tiles)
  const int ci = blockIdx.z;         // 0..3
  const int q0 = qt << 6;
  const int nc = (q0 + 64 + 511) >> 9;
  if (ci >= nc) return;
  const int k_lo = ci << 9;
  const int k_hi = min(k_lo + 512, q0 + 64);
  const int nsteps = (k_hi - k_lo + 127) >> 7;

  __shared__ u16 kS[128 * 72];       // K tile [tok][64+8 pad]; reused as O bounce
  __shared__ u16 vS[64 * 136];       // V^T tile [f][128+8 pad]
  const int tid = threadIdx.x, L = tid & 63, w = tid >> 6;
  const int m = L & 15, quad = L >> 4;
  const int h = combo >> 1, b = combo & 1;
  const size_t tb = (size_t)b * 2048;
  const size_t hbase = (size_t)h * 4096;
  const int qg = q0 + w * 16 + m;    // this lane's global q (column)

  // Q B-frags: lane n=q holds feats quad*4+j per 16-feat group
  s16x4 qf[4];
  {
    const u16* qp = qh + ((hbase + tb + (size_t)(q0 + w * 16 + m)) << 6) + quad * 4;
#pragma unroll
    for (int fg = 0; fg < 4; fg++) qf[fg] = *(const s16x4*)(qp + fg * 16);
  }
  const s16x4 ones = {(short)0x3F80, (short)0x3F80, (short)0x3F80, (short)0x3F80};

  f32x4 zero4 = {0.f, 0.f, 0.f, 0.f};
  f32x4 O[4];                        // O^T: lane q, f = ft*16 + quad*4 + r
#pragma unroll
  for (int ft = 0; ft < 4; ft++) O[ft] = zero4;
  f32x4 lacc = zero4;                // l[q] in every row
  float mrow = -30000.f;

  const int krow[4] = { (0*256+tid) >> 3, (1*256+tid) >> 3, (2*256+tid) >> 3, (3*256+tid) >> 3 };
  const int kc = tid & 7;
  const int vf[4] = { (0*256+tid) >> 4, (1*256+tid) >> 4, (2*256+tid) >> 4, (3*256+tid) >> 4 };
  const int vc = tid & 15;

  int4 kr[4], vr[4];
#pragma unroll
  for (int i = 0; i < 4; i++) {
    kr[i] = *(const int4*)(kh + ((hbase + tb + k_lo + krow[i]) << 6) + kc * 8);
    vr[i] = *(const int4*)(vT + (((size_t)h * 64 + vf[i]) << 12) + tb + k_lo + vc * 8);
  }

  for (int j = 0; j < nsteps; j++) {
    const int k0 = k_lo + (j << 7);
    __syncthreads();
#pragma unroll
    for (int i = 0; i < 4; i++) {
      *(int4*)&kS[krow[i] * 72 + kc * 8] = kr[i];
      *(int4*)&vS[vf[i] * 136 + vc * 8] = vr[i];
    }
    __syncthreads();
    if (j + 1 < nsteps) {
      const int k1 = k_lo + ((j + 1) << 7);
#pragma unroll
      for (int i = 0; i < 4; i++) {
        kr[i] = *(const int4*)(kh + ((hbase + tb + k1 + krow[i]) << 6) + kc * 8);
        vr[i] = *(const int4*)(vT + (((size_t)h * 64 + vf[i]) << 12) + tb + k1 + vc * 8);
      }
    }
    // S^T = K·Q^T : lane holds col q=m, rows ktok = kt*16 + quad*4 + r
    f32x4 sc[8];
#pragma unroll
    for (int kt = 0; kt < 8; kt++) {
      f32x4 t = zero4;
#pragma unroll
      for (int fg = 0; fg < 4; fg++) {
        s16x4 ka = *(const s16x4*)&kS[(kt * 16 + m) * 72 + fg * 16 + quad * 4];
        t = mfma16(ka, qf[fg], t);
      }
      sc[kt] = t;
    }
    if (k0 + 128 > q0) {   // touches diagonal: causal mask
#pragma unroll
      for (int kt = 0; kt < 8; kt++)
#pragma unroll
        for (int r = 0; r < 4; r++) {
          int ktok = k0 + kt * 16 + quad * 4 + r;
          if (ktok > qg) sc[kt][r] = -30000.f;
        }
    }
    // per-lane max over 32 regs, then combine the 4 quads (2 shuffles)
    float mx = sc[0][0];
#pragma unroll
    for (int kt = 0; kt < 8; kt++)
#pragma unroll
      for (int r = 0; r < 4; r++) mx = fmaxf(mx, sc[kt][r]);
    mx = fmaxf(mx, __shfl_xor(mx, 16, 64));
    mx = fmaxf(mx, __shfl_xor(mx, 32, 64));
    float mnew = fmaxf(mrow, mx);
    float alpha = __builtin_amdgcn_exp2f(mrow - mnew);
    mrow = mnew;
#pragma unroll
    for (int ft = 0; ft < 4; ft++) O[ft] *= alpha;
    lacc *= alpha;
    // P^T = exp2(S^T - m): C/D regs are directly the next MFMA's B-operand
    s16x4 pb[8];
#pragma unroll
    for (int kt = 0; kt < 8; kt++)
#pragma unroll
      for (int r = 0; r < 4; r++)
        pb[kt][r] = (short)f2bf(__builtin_amdgcn_exp2f(sc[kt][r] - mnew));
    // O^T += V^T·P^T ; l += 1·P^T
#pragma unroll
    for (int kt = 0; kt < 8; kt++) {
      lacc = mfma16(ones, pb[kt], lacc);
#pragma unroll
      for (int ft = 0; ft < 4; ft++) {
        s16x4 va = *(const s16x4*)&vS[(ft * 16 + m) * 136 + kt * 16 + quad * 4];
        O[ft] = mfma16(va, pb[kt], O[ft]);
      }
    }
  }

  // O^T -> LDS bounce (kS reused, stride 72 keeps int4 16B-aligned) -> global
  __syncthreads();
#pragma unroll
  for (int ft = 0; ft < 4; ft++) {
    s16x4 o4;
#pragma unroll
    for (int r = 0; r < 4; r++) o4[r] = (short)f2bf(O[ft][r]);
    *(s16x4*)&kS[(w * 16 + m) * 72 + ft * 16 + quad * 4] = o4;
  }
  __syncthreads();
  const int slot = (combo * 32 + qt) * 4 + ci;
  u16* op = Opart + ((size_t)slot << 12);
#pragma unroll
  for (int it = 0; it < 2; it++) {
    int idx = it * 256 + tid;
    int row = idx >> 3, c = idx & 7;
    *(int4*)&op[row * 64 + c * 8] = *(const int4*)&kS[row * 72 + c * 8];
  }
  if (quad == 0) {
    stats[slot * 128 + w * 16 + m]      = mrow;
    stats[slot * 128 + 64 + w * 16 + m] = lacc[0];
  }
}

// merge partials -> z [t][1024]
__global__ __launch_bounds__(256) void attn_merge(
    const u16* __restrict__ Opart, const float* __restrict__ stats,
    u16* __restrict__ z) {
  const int combo = blockIdx.x, qt = blockIdx.y;
  const int h = combo >> 1, b = combo & 1;
  const int q0 = qt << 6;
  const int nc = (q0 + 64 + 511) >> 9;
  const int tid = threadIdx.x;
  const int t = tid >> 2, f0 = (tid & 3) << 4;
  const int slot0 = (combo * 32 + qt) * 4;
  float M = -3e4f;
  for (int ci = 0; ci < nc; ci++)
    M = fmaxf(M, stats[(slot0 + ci) * 128 + t]);
  float acc[16];
#pragma unroll
  for (int e = 0; e < 16; e++) acc[e] = 0.f;
  float ltot = 0.f;
  for (int ci = 0; ci < nc; ci++) {
    float mi = stats[(slot0 + ci) * 128 + t];
    float li = stats[(slot0 + ci) * 128 + 64 + t];
    float wgt = exp2f(mi - M);
    ltot += wgt * li;
    const u16* op = Opart + (((size_t)(slot0 + ci)) << 12) + t * 64 + f0;
    union { int4 v; u16 u[8]; } a0, a1;
    a0.v = *(const int4*)op;
    a1.v = *(const int4*)(op + 8);
#pragma unroll
    for (int e = 0; e < 8; e++) {
      acc[e]     += wgt * bf2f(a0.u[e]);
      acc[8 + e] += wgt * bf2f(a1.u[e]);
    }
  }
  float inv = 1.f / ltot;
  union { int4 v; u16 u[8]; } o0, o1;
#pragma unroll
  for (int e = 0; e < 8; e++) {
    o0.u[e] = f2bf(acc[e] * inv);
    o1.u[e] = f2bf(acc[8 + e] * inv);
  }
  size_t tok = (size_t)b * 2048 + q0 + t;
  *(int4*)&z[tok * 1024 + h * 64 + f0]     = o0.v;
  *(int4*)&z[tok * 1024 + h * 64 + f0 + 8] = o1.v;
}

// ---------------------------------------------------------------------------
extern "C" void kernel_launch(void* const* d_in, const int* in_sizes, int n_in,
                              void* d_out, int out_size, void* d_ws, size_t ws_size,
                              hipStream_t stream) {
  (void)in_sizes; (void)n_in; (void)out_size; (void)ws_size;
  const void* resid_pre = d_in[0];
  const void* ln1_w = d_in[1];
  const void* ln1_b = d_in[2];
  const void* W_Q   = d_in[3];
  const void* b_Q   = d_in[4];
  const void* W_K   = d_in[5];
  const void* b_K   = d_in[6];
  const void* W_V   = d_in[7];
  const void* b_V   = d_in[8];
  const void* W_O   = d_in[9];
  const void* b_O   = d_in[10];
  const void* ln2_w = d_in[11];
  const void* ln2_b = d_in[12];
  const void* W_in  = d_in[13];
  const void* b_in  = d_in[14];
  const void* W_out = d_in[15];
  const void* b_out = d_in[16];

  char* p = (char*)d_ws;
  auto alloc = [&](size_t bytes) {
    char* r = p; p += (bytes + 255) & ~(size_t)255; return (void*)r;
  };
  int*   flag      = (int*)  alloc(256);
  u16*   WqkvT     = (u16*)  alloc(3072ull * 1024 * 2);
  u16*   WoT       = (u16*)  alloc(1024ull * 1024 * 2);
  u16*   WinT      = (u16*)  alloc(4096ull * 1024 * 2);
  u16*   WoutT     = (u16*)  alloc(1024ull * 4096 * 2);
  float* biases    = (float*)alloc(9216 * 4);
  u16*   xn        = (u16*)  alloc(4096ull * 1024 * 2);  // reused as z
  u16*   q_hm      = (u16*)  alloc(16ull * 4096 * 64 * 2);
  u16*   k_hm      = (u16*)  alloc(16ull * 4096 * 64 * 2);
  u16*   vTws      = (u16*)  alloc(16ull * 64 * 4096 * 2);
  float* resid_mid = (float*)alloc(4096ull * 1024 * 4);
  u16*   h2        = (u16*)  alloc(4096ull * 1024 * 2);  // attn stats before ln2
  u16*   act       = (u16*)  alloc(4096ull * 4096 * 2);  // attn partials before MLP
  u16*   z = xn;
  u16*   Opart = act;              // 4096 slots x 4096 u16 = 32 MB (exact)
  float* stats = (float*)h2;       // 4096 slots x 128 fp32 = 2 MB < 8 MB

  detect_dtype<<<1, 256, 0, stream>>>((const unsigned int*)resid_pre, flag);

  pack_qkv_tiled<<<dim3(16, 48), 256, 0, stream>>>(flag, W_Q, W_K, W_V, WqkvT);
  transpose_tiled<<<dim3(16, 16), 256, 0, stream>>>(flag, W_O,   WoT,   1024, 1024);
  transpose_tiled<<<dim3(64, 16), 256, 0, stream>>>(flag, W_in,  WinT,  1024, 4096);
  transpose_tiled<<<dim3(16, 64), 256, 0, stream>>>(flag, W_out, WoutT, 4096, 1024);
  pack_biases<<<36, 256, 0, stream>>>(flag, b_Q, b_K, b_V, b_O, b_in, b_out, biases);

  ln_fwd<0><<<4096, 256, 0, stream>>>(flag, resid_pre, ln1_w, ln1_b, xn);
  // qkv -> head-major q/k + transposed v. grid: 8 XCD x SH=4 rows x 24 cols
  gemm_bt<4, 128><<<768, 256, 0, stream>>>(
      flag, xn, WqkvT, biases, nullptr, q_hm, k_hm, vTws, 4096, 3072, 1024, 2);
  // split-K causal flash attention -> partials -> merge -> z
  attn_part<<<dim3(32, 32, 4), 256, 0, stream>>>(q_hm, k_hm, vTws, Opart, stats);
  attn_merge<<<dim3(32, 32), 256, 0, stream>>>(Opart, stats, z);
  // resid_mid = resid_pre + z @ W_O + b_O   (fp32). 8 XCD x SH=8 x 8 cols
  gemm_bt<2, 64><<<512, 256, 0, stream>>>(
      flag, z, WoT, biases + 3072, resid_pre, resid_mid, nullptr, nullptr, 4096, 1024, 1024, 3);
  ln_fwd<1><<<4096, 256, 0, stream>>>(flag, resid_mid, ln2_w, ln2_b, h2);
  // act = relu(h2 @ W_in + b_in). 8 XCD x SH=4 x 32 cols
  gemm_bt<1, 128><<<1024, 256, 0, stream>>>(
      flag, h2, WinT, biases + 4096, nullptr, act, nullptr, nullptr, 4096, 4096, 1024, 2);
  // out = resid_mid + act @ W_out + b_out. 8 XCD x SH=8 x 8 cols
  gemm_bt<3, 64><<<512, 256, 0, stream>>>(
      flag, act, WoutT, biases + 8192, resid_mid, d_out, nullptr, nullptr, 4096, 1024, 4096, 3);
}

// Round 8
// 432.617 us; speedup vs baseline: 1.5607x; 1.1524x over previous
//
#include <hip/hip_runtime.h>
#include <stdint.h>

// ---------------------------------------------------------------------------
// TransformerBlock on MI355X (gfx950). Runtime dtype detection (fp32 vs bf16
// inputs), bf16-MFMA internal compute, fp32 accumulation + fp32 residual path.
// B=2 S=2048 D=1024 H=16 K=64 MLP=4096; tokens M = 4096.
// R8: attention hybrid MFMA shapes — QK^T via 16x16x32 (b128 K reads),
// PV via 16x16x16 with permuted V staging (b128 V reads), P^T stays in
// registers; l via in-loop adds. GEMMs: register-prefetch double-buffer
// staging (int4 loads one compute-phase ahead) instead of global_load_lds.
// ---------------------------------------------------------------------------

typedef unsigned short u16;
typedef __bf16 bf16x8 __attribute__((ext_vector_type(8)));
typedef __bf16 bf16x4 __attribute__((ext_vector_type(4)));
typedef __bf16 bf16x2 __attribute__((ext_vector_type(2)));
typedef short  s16x4  __attribute__((ext_vector_type(4)));
typedef float  f32x4  __attribute__((ext_vector_type(4)));

#define QSCALE 0.18033688011112042f   // (1/sqrt(64)) * log2(e): softmax via exp2

__device__ __forceinline__ float bf2f(unsigned int u) {
  union { unsigned int u; float f; } v; v.u = u << 16; return v.f;
}
__device__ __forceinline__ u16 f2bf(float f) {
  union { float f; unsigned int u; } v; v.f = f;
  unsigned int r = v.u + 0x7FFFu + ((v.u >> 16) & 1u);   // RNE
  return (u16)(r >> 16);
}
__device__ __forceinline__ unsigned pkbf(float lo, float hi) {
#if __has_builtin(__builtin_amdgcn_cvt_pk_bf16_f32)
  bf16x2 t = __builtin_amdgcn_cvt_pk_bf16_f32(lo, hi);
  return __builtin_bit_cast(unsigned, t);
#else
  return (unsigned)f2bf(lo) | ((unsigned)f2bf(hi) << 16);
#endif
}
__device__ __forceinline__ float loadf(const void* p, size_t i, int isf) {
  return isf ? ((const float*)p)[i] : bf2f(((const u16*)p)[i]);
}

// 16x16x16 bf16 MFMA wrapper
__device__ __forceinline__ f32x4 mfma16(s16x4 a, s16x4 b, f32x4 c) {
#if __has_builtin(__builtin_amdgcn_mfma_f32_16x16x16_bf16)
  return __builtin_amdgcn_mfma_f32_16x16x16_bf16(
      __builtin_bit_cast(bf16x4, a), __builtin_bit_cast(bf16x4, b), c, 0, 0, 0);
#else
  return __builtin_amdgcn_mfma_f32_16x16x16bf16_1k(a, b, c, 0, 0, 0);
#endif
}

// ---------------------------------------------------------------------------
__global__ __launch_bounds__(256) void detect_dtype(
    const unsigned int* __restrict__ x, int* __restrict__ flag) {
  __shared__ int cnt;
  if (threadIdx.x == 0) cnt = 0;
  __syncthreads();
  int c = 0;
  for (int i = threadIdx.x; i < 512; i += 256) {
    unsigned int e = (x[i] >> 23) & 0xFFu;
    if (e >= 97u && e <= 157u) c++;
  }
  atomicAdd(&cnt, c);
  __syncthreads();
  if (threadIdx.x == 0) *flag = (cnt > 384) ? 1 : 0;
}

// ---------------------------------------------------------------------------
// Tiled transposes: 64x64 tiles through LDS (stride-65 pad -> 2-way = free).
// ---------------------------------------------------------------------------
__global__ __launch_bounds__(256) void pack_qkv_tiled(
    const int* __restrict__ flagp,
    const void* __restrict__ Wq, const void* __restrict__ Wk, const void* __restrict__ Wv,
    u16* __restrict__ WT) {
  __shared__ float t[64][65];
  const int isf = *flagp;
  const int tid = threadIdx.x;
  const int mh = blockIdx.y;            // mat*16 + h
  const int mat = mh >> 4, h = mh & 15;
  const int d0 = blockIdx.x << 6;       // d-tile
  const void* src = (mat == 0) ? Wq : (mat == 1) ? Wk : Wv;
  const float scale = (mat == 0) ? QSCALE : 1.f;
  const int lane = tid & 63, rr = tid >> 6;
  const size_t sbase = ((size_t)h << 16) + lane;
#pragma unroll
  for (int i = 0; i < 16; i++) {
    int d = i * 4 + rr;
    t[d][lane] = loadf(src, sbase + (size_t)(d0 + d) * 64, isf) * scale;
  }
  __syncthreads();
#pragma unroll
  for (int i = 0; i < 16; i++) {
    int k = i * 4 + rr;
    WT[((size_t)((mat << 10) + (h << 6) + k) << 10) + d0 + lane] = f2bf(t[lane][k]);
  }
}

__global__ __launch_bounds__(256) void transpose_tiled(
    const int* __restrict__ flagp, const void* __restrict__ src,
    u16* __restrict__ dst, int R, int C) {
  __shared__ float t[64][65];
  const int isf = *flagp;
  const int tid = threadIdx.x;
  const int c0 = blockIdx.x << 6, r0 = blockIdx.y << 6;
  const int lane = tid & 63, rr = tid >> 6;
#pragma unroll
  for (int i = 0; i < 16; i++) {
    int r = i * 4 + rr;
    t[r][lane] = loadf(src, (size_t)(r0 + r) * C + c0 + lane, isf);
  }
  __syncthreads();
#pragma unroll
  for (int i = 0; i < 16; i++) {
    int c = i * 4 + rr;
    dst[(size_t)(c0 + c) * R + r0 + lane] = f2bf(t[lane][c]);
  }
}

__global__ __launch_bounds__(256) void pack_biases(
    const int* __restrict__ flagp,
    const void* bq, const void* bk, const void* bv,
    const void* bO, const void* bin, const void* bout,
    float* __restrict__ out) {
  const int isf = *flagp;
  int i = blockIdx.x * 256 + threadIdx.x;
  float v;
  if (i < 1024)      v = loadf(bq,   i,        isf) * QSCALE;
  else if (i < 2048) v = loadf(bk,   i - 1024, isf);
  else if (i < 3072) v = loadf(bv,   i - 2048, isf);
  else if (i < 4096) v = loadf(bO,   i - 3072, isf);
  else if (i < 8192) v = loadf(bin,  i - 4096, isf);
  else               v = loadf(bout, i - 8192, isf);
  out[i] = v;
}

// ---------------------------------------------------------------------------
template<int SRC>
__global__ __launch_bounds__(256) void ln_fwd(
    const int* __restrict__ flagp, const void* __restrict__ xin,
    const void* __restrict__ w, const void* __restrict__ b,
    u16* __restrict__ out) {
  const int isf = *flagp;
  const int row = blockIdx.x, tid = threadIdx.x;
  const int col = tid << 2;
  const size_t base = ((size_t)row << 10) + col;
  float v[4];
#pragma unroll
  for (int i = 0; i < 4; i++)
    v[i] = (SRC == 1) ? ((const float*)xin)[base + i] : loadf(xin, base + i, isf);
  float s  = v[0] + v[1] + v[2] + v[3];
  float ss = v[0]*v[0] + v[1]*v[1] + v[2]*v[2] + v[3]*v[3];
#pragma unroll
  for (int mk = 32; mk >= 1; mk >>= 1) {
    s  += __shfl_xor(s,  mk, 64);
    ss += __shfl_xor(ss, mk, 64);
  }
  __shared__ float red[8];
  if ((tid & 63) == 0) { red[tid >> 6] = s; red[4 + (tid >> 6)] = ss; }
  __syncthreads();
  float S  = red[0] + red[1] + red[2] + red[3];
  float SS = red[4] + red[5] + red[6] + red[7];
  float mean = S * (1.f / 1024.f);
  float var  = SS * (1.f / 1024.f) - mean * mean;
  float rstd = rsqrtf(var + 1e-5f);
  u16 e[4];
#pragma unroll
  for (int i = 0; i < 4; i++) {
    float wv = loadf(w, col + i, isf);
    float bv = loadf(b, col + i, isf);
    e[i] = f2bf((v[i] - mean) * rstd * wv + bv);
  }
  uint2 o;
  o.x = (unsigned)e[0] | ((unsigned)e[1] << 16);
  o.y = (unsigned)e[2] | ((unsigned)e[3] << 16);
  *(uint2*)(out + base) = o;
}

// ---------------------------------------------------------------------------
// GEMM C[M,N] = A[M,K] @ BT[N,K]^T + bias. 256 thr / 4 waves.
// TM=128: wave tile 64x64 (acc 4x4). TM=64: wave tile 32x64 (acc 2x4).
// Staging: int4 register prefetch (one compute phase ahead) -> ds_write,
// so global latency hides behind MFMA instead of draining at the barrier.
// XCD-swizzled 1-D grid: xcd=Lb&7 owns a row stripe; columns advance in
// lockstep across XCDs.
// MODE 1: relu+bf16; 2: +flagged resid -> fp32; 3: +fp32 resid -> flagged out
// MODE 4: QKV epilogue -> q_hm[h][t][64], k_hm, vT[h][f][4096]
// ---------------------------------------------------------------------------
template<int MODE, int TM>
__global__ __launch_bounds__(256) void gemm_bt(
    const int* __restrict__ flagp,
    const u16* __restrict__ A, const u16* __restrict__ BT,
    const float* __restrict__ bias, const void* __restrict__ resid,
    void* __restrict__ out, void* __restrict__ out2, void* __restrict__ out3,
    int M, int N, int K, int SHL) {
  constexpr int WR = TM / 32;          // row-frags per wave
  __shared__ u16 as[TM * 32];
  __shared__ u16 bs[128 * 32];
  int isf = 0;
  if (MODE == 2 || MODE == 3) isf = *flagp;
  const int Lb = blockIdx.x;
  const int xcd = Lb & 7, sidx = Lb >> 3;
  const int SH = 1 << SHL;
  const int by = xcd * SH + (sidx & (SH - 1));
  const int bx = sidx >> SHL;
  const int tid = threadIdx.x;
  const int L = tid & 63, w = tid >> 6;
  const int wm = (w >> 1) * (TM >> 1), wn = (w & 1) << 6;
  const int row0 = by * TM, col0 = bx << 7;
  const int m = L & 15, quad = L >> 4;

  f32x4 zero4 = {0.f, 0.f, 0.f, 0.f};
  f32x4 acc[WR][4];
#pragma unroll
  for (int i = 0; i < WR; i++)
#pragma unroll
    for (int j = 0; j < 4; j++) acc[i][j] = zero4;

  const int tm = tid >> 2;
  const int tk = (tid & 3) << 3;
  const u16* Ag  = A  + (size_t)(row0 + tm) * K + tk;
  const u16* Ag2 = Ag + (size_t)64 * K;          // TM==128 only
  const u16* Bg  = BT + (size_t)(col0 + tm) * K + tk;
  const u16* Bg2 = Bg + (size_t)64 * K;
  u16* asl  = &as[tid * 8];
  u16* asl2 = &as[2048 + tid * 8];
  u16* bsl  = &bs[tid * 8];
  u16* bsl2 = &bs[2048 + tid * 8];

  const int aoff = (wm + m) * 32 + quad * 8;
  const int boff = (wn + m) * 32 + quad * 8;

  int4 ar0, ar1, br0, br1;
  ar0 = *(const int4*)Ag;
  if (TM == 128) ar1 = *(const int4*)Ag2;
  br0 = *(const int4*)Bg;
  br1 = *(const int4*)Bg2;

  for (int kk = 0; kk < K; kk += 32) {
    __syncthreads();                    // LDS consumers of prev step done
    *(int4*)asl = ar0;
    if (TM == 128) *(int4*)asl2 = ar1;
    *(int4*)bsl = br0;
    *(int4*)bsl2 = br1;
    __syncthreads();
    if (kk + 32 < K) {                  // prefetch next step into registers
      ar0 = *(const int4*)(Ag + kk + 32);
      if (TM == 128) ar1 = *(const int4*)(Ag2 + kk + 32);
      br0 = *(const int4*)(Bg + kk + 32);
      br1 = *(const int4*)(Bg2 + kk + 32);
    }
    bf16x8 af[WR], bfr[4];
#pragma unroll
    for (int i = 0; i < WR; i++) af[i]  = *(const bf16x8*)&as[aoff + i * 512];
#pragma unroll
    for (int j = 0; j < 4; j++) bfr[j] = *(const bf16x8*)&bs[boff + j * 512];
#pragma unroll
    for (int i = 0; i < WR; i++)
#pragma unroll
      for (int j = 0; j < 4; j++)
        acc[i][j] = __builtin_amdgcn_mfma_f32_16x16x32_bf16(af[i], bfr[j], acc[i][j], 0, 0, 0);
  }

#pragma unroll
  for (int j = 0; j < 4; j++) {
    const int col = col0 + wn + j * 16 + m;
    const float bval = bias[col];
    if (MODE == 4) {
      const int sel = col >> 10;
      const int hh  = (col >> 6) & 15;
      const int f   = col & 63;
#pragma unroll
      for (int i = 0; i < WR; i++) {
        const int rowb = row0 + wm + i * 16 + quad * 4;
        if (sel < 2) {
          u16* dst = (u16*)(sel ? out2 : out);
#pragma unroll
          for (int r = 0; r < 4; r++)
            dst[((((size_t)hh << 12) + rowb + r) << 6) + f] = f2bf(acc[i][j][r] + bval);
        } else {
          uint2 o;
          o.x = pkbf(acc[i][j][0] + bval, acc[i][j][1] + bval);
          o.y = pkbf(acc[i][j][2] + bval, acc[i][j][3] + bval);
          *(uint2*)&((u16*)out3)[(((size_t)hh * 64 + f) << 12) + rowb] = o;
        }
      }
    } else {
#pragma unroll
      for (int i = 0; i < WR; i++) {
        const int rowb = row0 + wm + i * 16 + quad * 4;
#pragma unroll
        for (int r = 0; r < 4; r++) {
          float vv = acc[i][j][r] + bval;
          size_t idx = (size_t)(rowb + r) * N + col;
          if (MODE == 1) {
            ((u16*)out)[idx] = f2bf(fmaxf(vv, 0.f));
          } else if (MODE == 2) {
            ((float*)out)[idx] = vv + loadf(resid, idx, isf);
          } else if (MODE == 3) {
            float o = vv + ((const float*)resid)[idx];
            if (isf) ((float*)out)[idx] = o;
            else     ((u16*)out)[idx]   = f2bf(o);
          }
        }
      }
    }
  }
}

// ---------------------------------------------------------------------------
// Flash attention, split-K, hybrid-MFMA transposed form.
// Block = (combo=h*2+b, qt64, ci): 64 q (4 waves x 16, q = lane&15 column)
// vs k-chunk <=512 (<=4 steps of 128).
// QK^T: S^T = K·Q^T via 16x16x32 (K A-frags contiguous 16B -> ds_read_b128).
// Its C/D layout == 16x16x16 C/D == 16x16x16 B-operand, so P^T feeds
// O^T = V^T·P^T via 16x16x16 from registers. V staged PERMUTED
// (c' = quad*32 + kt*4 + j) so PV A-frags are also b128 reads.
// l accumulated during the exp loop (+2 shuffles). 2 shuffles for max.
// ---------------------------------------------------------------------------
__global__ __launch_bounds__(256, 3) void attn_part(
    const u16* __restrict__ qh, const u16* __restrict__ kh,
    const u16* __restrict__ vT, u16* __restrict__ Opart,
    float* __restrict__ stats) {
  const int combo = blockIdx.x;      // h*2 + b
  const int qt = blockIdx.y;         // 0..31 (64-row q-tiles)
  const int ci = blockIdx.z;         // 0..3
  const int q0 = qt << 6;
  const int nc = (q0 + 64 + 511) >> 9;
  if (ci >= nc) return;
  const int k_lo = ci << 9;
  const int k_hi = min(k_lo + 512, q0 + 64);
  const int nsteps = (k_hi - k_lo + 127) >> 7;

  __shared__ u16 kS[128 * 72];       // K tile [tok][64+8 pad]; reused as O bounce
  __shared__ u16 vS[64 * 136];       // V^T tile [f][128 permuted + 8 pad]
  const int tid = threadIdx.x, L = tid & 63, w = tid >> 6;
  const int m = L & 15, quad = L >> 4;
  const int h = combo >> 1, b = combo & 1;
  const size_t tb = (size_t)b * 2048;
  const size_t hbase = (size_t)h * 4096;
  const int qg = q0 + w * 16 + m;    // this lane's global q (column)

  // Q as 16x16x32 B-frags: lane n=q, k=feat quad*8+j (two 32-feat chunks)
  bf16x8 qb0, qb1;
  {
    const u16* qp = qh + ((hbase + tb + (size_t)qg) << 6) + quad * 8;
    qb0 = *(const bf16x8*)qp;
    qb1 = *(const bf16x8*)(qp + 32);
  }

  f32x4 zero4 = {0.f, 0.f, 0.f, 0.f};
  f32x4 O[4];                        // O^T: lane q, f = ft*16 + quad*4 + r
#pragma unroll
  for (int ft = 0; ft < 4; ft++) O[ft] = zero4;
  float mrow = -30000.f, lrow = 0.f;

  const int krow[4] = { (0*256+tid) >> 3, (1*256+tid) >> 3, (2*256+tid) >> 3, (3*256+tid) >> 3 };
  const int kc = tid & 7;
  const int vf[4] = { (0*256+tid) >> 4, (1*256+tid) >> 4, (2*256+tid) >> 4, (3*256+tid) >> 4 };
  const int vc = tid & 15;
  // permuted V column bases for the two 4-elem halves of each int4
  const int vq = (vc & 1) << 1;             // quad base 2*(vc&1)
  const int vk4 = (vc >> 1) << 2;           // kt*4
  const int vc0 = (vq << 5) + vk4;          // quad*32 + kt*4
  const int vc1 = ((vq + 1) << 5) + vk4;

  int4 kr[4], vr[4];
#pragma unroll
  for (int i = 0; i < 4; i++) {
    kr[i] = *(const int4*)(kh + ((hbase + tb + k_lo + krow[i]) << 6) + kc * 8);
    vr[i] = *(const int4*)(vT + (((size_t)h * 64 + vf[i]) << 12) + tb + k_lo + vc * 8);
  }

  for (int j = 0; j < nsteps; j++) {
    const int k0 = k_lo + (j << 7);
    __syncthreads();
#pragma unroll
    for (int i = 0; i < 4; i++) {
      *(int4*)&kS[krow[i] * 72 + kc * 8] = kr[i];
      union { int4 v; s16x4 hh[2]; } tv; tv.v = vr[i];
      *(s16x4*)&vS[vf[i] * 136 + vc0] = tv.hh[0];
      *(s16x4*)&vS[vf[i] * 136 + vc1] = tv.hh[1];
    }
    __syncthreads();
    if (j + 1 < nsteps) {
      const int k1 = k_lo + ((j + 1) << 7);
#pragma unroll
      for (int i = 0; i < 4; i++) {
        kr[i] = *(const int4*)(kh + ((hbase + tb + k1 + krow[i]) << 6) + kc * 8);
        vr[i] = *(const int4*)(vT + (((size_t)h * 64 + vf[i]) << 12) + tb + k1 + vc * 8);
      }
    }
    // S^T = K·Q^T via 16x16x32: lane col q=m, rows ktok = kt*16 + quad*4 + r
    f32x4 sc[8];
#pragma unroll
    for (int kt = 0; kt < 8; kt++) {
      const u16* kp = &kS[(kt * 16 + m) * 72 + quad * 8];
      bf16x8 ka0 = *(const bf16x8*)kp;
      bf16x8 ka1 = *(const bf16x8*)(kp + 32);
      f32x4 t = zero4;
      t = __builtin_amdgcn_mfma_f32_16x16x32_bf16(ka0, qb0, t, 0, 0, 0);
      t = __builtin_amdgcn_mfma_f32_16x16x32_bf16(ka1, qb1, t, 0, 0, 0);
      sc[kt] = t;
    }
    if (k0 + 128 > q0) {   // touches diagonal: causal mask
#pragma unroll
      for (int kt = 0; kt < 8; kt++)
#pragma unroll
        for (int r = 0; r < 4; r++) {
          int ktok = k0 + kt * 16 + quad * 4 + r;
          if (ktok > qg) sc[kt][r] = -30000.f;
        }
    }
    // per-lane max over 32 regs + 2 shuffles (q fixed per lane)
    float mx = sc[0][0];
#pragma unroll
    for (int kt = 0; kt < 8; kt++)
#pragma unroll
      for (int r = 0; r < 4; r++) mx = fmaxf(mx, sc[kt][r]);
    mx = fmaxf(mx, __shfl_xor(mx, 16, 64));
    mx = fmaxf(mx, __shfl_xor(mx, 32, 64));
    float mnew = fmaxf(mrow, mx);
    float alpha = __builtin_amdgcn_exp2f(mrow - mnew);
    mrow = mnew;
    // P^T = exp2(S^T - m): pack to bf16 B-frags; accumulate l inline
    s16x4 pb[8];
    float sum = 0.f;
#pragma unroll
    for (int kt = 0; kt < 8; kt++) {
      float e0 = __builtin_amdgcn_exp2f(sc[kt][0] - mnew);
      float e1 = __builtin_amdgcn_exp2f(sc[kt][1] - mnew);
      float e2 = __builtin_amdgcn_exp2f(sc[kt][2] - mnew);
      float e3 = __builtin_amdgcn_exp2f(sc[kt][3] - mnew);
      sum += (e0 + e1) + (e2 + e3);
      union { uint2 u; s16x4 hh; } pu;
      pu.u.x = pkbf(e0, e1);
      pu.u.y = pkbf(e2, e3);
      pb[kt] = pu.hh;
    }
    sum += __shfl_xor(sum, 16, 64);
    sum += __shfl_xor(sum, 32, 64);
    lrow = lrow * alpha + sum;
#pragma unroll
    for (int ft = 0; ft < 4; ft++) O[ft] *= alpha;
    // O^T += V^T·P^T via 16x16x16; V A-frags read b128 (2 frags per read)
#pragma unroll
    for (int ft = 0; ft < 4; ft++) {
      const u16* vp = &vS[(ft * 16 + m) * 136 + quad * 32];
#pragma unroll
      for (int pr = 0; pr < 4; pr++) {
        union { bf16x8 v; s16x4 hh[2]; } u;
        u.v = *(const bf16x8*)(vp + pr * 8);
        O[ft] = mfma16(u.hh[0], pb[2 * pr],     O[ft]);
        O[ft] = mfma16(u.hh[1], pb[2 * pr + 1], O[ft]);
      }
    }
  }

  // O^T -> LDS bounce (kS reused) -> coalesced global stores
  __syncthreads();
#pragma unroll
  for (int ft = 0; ft < 4; ft++) {
    union { uint2 u; s16x4 hh; } o4;
    o4.u.x = pkbf(O[ft][0], O[ft][1]);
    o4.u.y = pkbf(O[ft][2], O[ft][3]);
    *(s16x4*)&kS[(w * 16 + m) * 72 + ft * 16 + quad * 4] = o4.hh;
  }
  __syncthreads();
  const int slot = (combo * 32 + qt) * 4 + ci;
  u16* op = Opart + ((size_t)slot << 12);
#pragma unroll
  for (int it = 0; it < 2; it++) {
    int idx = it * 256 + tid;
    int row = idx >> 3, c = idx & 7;
    *(int4*)&op[row * 64 + c * 8] = *(const int4*)&kS[row * 72 + c * 8];
  }
  if (quad == 0) {
    stats[slot * 128 + w * 16 + m]      = mrow;
    stats[slot * 128 + 64 + w * 16 + m] = lrow;
  }
}

// merge partials -> z [t][1024]
__global__ __launch_bounds__(256) void attn_merge(
    const u16* __restrict__ Opart, const float* __restrict__ stats,
    u16* __restrict__ z) {
  const int combo = blockIdx.x, qt = blockIdx.y;
  const int h = combo >> 1, b = combo & 1;
  const int q0 = qt << 6;
  const int nc = (q0 + 64 + 511) >> 9;
  const int tid = threadIdx.x;
  const int t = tid >> 2, f0 = (tid & 3) << 4;
  const int slot0 = (combo * 32 + qt) * 4;
  float M = -3e4f;
  for (int ci = 0; ci < nc; ci++)
    M = fmaxf(M, stats[(slot0 + ci) * 128 + t]);
  float acc[16];
#pragma unroll
  for (int e = 0; e < 16; e++) acc[e] = 0.f;
  float ltot = 0.f;
  for (int ci = 0; ci < nc; ci++) {
    float mi = stats[(slot0 + ci) * 128 + t];
    float li = stats[(slot0 + ci) * 128 + 64 + t];
    float wgt = exp2f(mi - M);
    ltot += wgt * li;
    const u16* op = Opart + (((size_t)(slot0 + ci)) << 12) + t * 64 + f0;
    union { int4 v; u16 u[8]; } a0, a1;
    a0.v = *(const int4*)op;
    a1.v = *(const int4*)(op + 8);
#pragma unroll
    for (int e = 0; e < 8; e++) {
      acc[e]     += wgt * bf2f(a0.u[e]);
      acc[8 + e] += wgt * bf2f(a1.u[e]);
    }
  }
  float inv = 1.f / ltot;
  union { int4 v; u16 u[8]; } o0, o1;
#pragma unroll
  for (int e = 0; e < 8; e++) {
    o0.u[e] = f2bf(acc[e] * inv);
    o1.u[e] = f2bf(acc[8 + e] * inv);
  }
  size_t tok = (size_t)b * 2048 + q0 + t;
  *(int4*)&z[tok * 1024 + h * 64 + f0]     = o0.v;
  *(int4*)&z[tok * 1024 + h * 64 + f0 + 8] = o1.v;
}

// ---------------------------------------------------------------------------
extern "C" void kernel_launch(void* const* d_in, const int* in_sizes, int n_in,
                              void* d_out, int out_size, void* d_ws, size_t ws_size,
                              hipStream_t stream) {
  (void)in_sizes; (void)n_in; (void)out_size; (void)ws_size;
  const void* resid_pre = d_in[0];
  const void* ln1_w = d_in[1];
  const void* ln1_b = d_in[2];
  const void* W_Q   = d_in[3];
  const void* b_Q   = d_in[4];
  const void* W_K   = d_in[5];
  const void* b_K   = d_in[6];
  const void* W_V   = d_in[7];
  const void* b_V   = d_in[8];
  const void* W_O   = d_in[9];
  const void* b_O   = d_in[10];
  const void* ln2_w = d_in[11];
  const void* ln2_b = d_in[12];
  const void* W_in  = d_in[13];
  const void* b_in  = d_in[14];
  const void* W_out = d_in[15];
  const void* b_out = d_in[16];

  char* p = (char*)d_ws;
  auto alloc = [&](size_t bytes) {
    char* r = p; p += (bytes + 255) & ~(size_t)255; return (void*)r;
  };
  int*   flag      = (int*)  alloc(256);
  u16*   WqkvT     = (u16*)  alloc(3072ull * 1024 * 2);
  u16*   WoT       = (u16*)  alloc(1024ull * 1024 * 2);
  u16*   WinT      = (u16*)  alloc(4096ull * 1024 * 2);
  u16*   WoutT     = (u16*)  alloc(1024ull * 4096 * 2);
  float* biases    = (float*)alloc(9216 * 4);
  u16*   xn        = (u16*)  alloc(4096ull * 1024 * 2);  // reused as z
  u16*   q_hm      = (u16*)  alloc(16ull * 4096 * 64 * 2);
  u16*   k_hm      = (u16*)  alloc(16ull * 4096 * 64 * 2);
  u16*   vTws      = (u16*)  alloc(16ull * 64 * 4096 * 2);
  float* resid_mid = (float*)alloc(4096ull * 1024 * 4);
  u16*   h2        = (u16*)  alloc(4096ull * 1024 * 2);  // attn stats before ln2
  u16*   act       = (u16*)  alloc(4096ull * 4096 * 2);  // attn partials before MLP
  u16*   z = xn;
  u16*   Opart = act;              // 4096 slots x 4096 u16 = 32 MB (exact)
  float* stats = (float*)h2;       // 4096 slots x 128 fp32 = 2 MB < 8 MB

  detect_dtype<<<1, 256, 0, stream>>>((const unsigned int*)resid_pre, flag);

  pack_qkv_tiled<<<dim3(16, 48), 256, 0, stream>>>(flag, W_Q, W_K, W_V, WqkvT);
  transpose_tiled<<<dim3(16, 16), 256, 0, stream>>>(flag, W_O,   WoT,   1024, 1024);
  transpose_tiled<<<dim3(64, 16), 256, 0, stream>>>(flag, W_in,  WinT,  1024, 4096);
  transpose_tiled<<<dim3(16, 64), 256, 0, stream>>>(flag, W_out, WoutT, 4096, 1024);
  pack_biases<<<36, 256, 0, stream>>>(flag, b_Q, b_K, b_V, b_O, b_in, b_out, biases);

  ln_fwd<0><<<4096, 256, 0, stream>>>(flag, resid_pre, ln1_w, ln1_b, xn);
  // qkv -> head-major q/k + transposed v. grid: 8 XCD x SH=4 rows x 24 cols
  gemm_bt<4, 128><<<768, 256, 0, stream>>>(
      flag, xn, WqkvT, biases, nullptr, q_hm, k_hm, vTws, 4096, 3072, 1024, 2);
  // split-K causal flash attention -> partials -> merge -> z
  attn_part<<<dim3(32, 32, 4), 256, 0, stream>>>(q_hm, k_hm, vTws, Opart, stats);
  attn_merge<<<dim3(32, 32), 256, 0, stream>>>(Opart, stats, z);
  // resid_mid = resid_pre + z @ W_O + b_O   (fp32). 8 XCD x SH=8 x 8 cols
  gemm_bt<2, 64><<<512, 256, 0, stream>>>(
      flag, z, WoT, biases + 3072, resid_pre, resid_mid, nullptr, nullptr, 4096, 1024, 1024, 3);
  ln_fwd<1><<<4096, 256, 0, stream>>>(flag, resid_mid, ln2_w, ln2_b, h2);
  // act = relu(h2 @ W_in + b_in). 8 XCD x SH=4 x 32 cols
  gemm_bt<1, 128><<<1024, 256, 0, stream>>>(
      flag, h2, WinT, biases + 4096, nullptr, act, nullptr, nullptr, 4096, 4096, 1024, 2);
  // out = resid_mid + act @ W_out + b_out. 8 XCD x SH=8 x 8 cols
  gemm_bt<3, 64><<<512, 256, 0, stream>>>(
      flag, act, WoutT, biases + 8192, resid_mid, d_out, nullptr, nullptr, 4096, 1024, 4096, 3);
}